// Round 1
// baseline (1674.852 us; speedup 1.0000x reference)
//
#include <hip/hip_runtime.h>

#define NEG_SLOPE 0.2f

// ---------------------------------------------------------------------------
// Projection: h = feat @ W + b  (128x128), plus per-head logit
//   logit[row][k] = sum_{dd<16} h[row][k*16+dd] * attn[k*32 + attn_off + dd]
// Block = 256 threads: 128 cols x 2 row-halves; 8 rows per chunk, 4 rows/thread.
// feat rows staged in LDS (broadcast reads); W streamed from L1/L2 (64 KB, hot).
// ---------------------------------------------------------------------------
template<bool STORE_H>
__global__ __launch_bounds__(256) void proj_kernel(
    const float* __restrict__ feat,   // [N,128]
    const float* __restrict__ W,      // [128,128]
    const float* __restrict__ b,      // [128]
    const float* __restrict__ attn,   // [8,32]
    float* __restrict__ h_out,        // [N,128] (unused if !STORE_H)
    float* __restrict__ logit,        // [N,8]
    int N, int attn_off)
{
    __shared__ float featl[8 * 128];
    __shared__ float lbuf[64];        // 8 rows x 8 heads
    const int t    = threadIdx.x;
    const int col  = t & 127;
    const int half = t >> 7;          // 0 or 1
    const int k    = col >> 4;
    const float bias  = b[col];
    const float acoef = attn[k * 32 + attn_off + (col & 15)];

    if (t < 64) lbuf[t] = 0.f;

    const int nChunks = (N + 7) >> 3;
    for (int chunk = blockIdx.x; chunk < nChunks; chunk += gridDim.x) {
        const int row0 = chunk << 3;
        {   // stage 8 feat rows (8*128 floats = 256 float4)
            const int r  = t >> 5;
            const int c4 = t & 31;
            const int row = row0 + r;
            float4 v = make_float4(0.f, 0.f, 0.f, 0.f);
            if (row < N) v = ((const float4*)(feat + (size_t)row * 128))[c4];
            ((float4*)featl)[t] = v;
        }
        __syncthreads();

        float acc0 = bias, acc1 = bias, acc2 = bias, acc3 = bias;
        const float* f = featl + half * 4 * 128;
        #pragma unroll 16
        for (int kk = 0; kk < 128; ++kk) {
            const float w = W[kk * 128 + col];      // coalesced, cache-hot
            acc0 = fmaf(f[kk],       w, acc0);
            acc1 = fmaf(f[128 + kk], w, acc1);
            acc2 = fmaf(f[256 + kk], w, acc2);
            acc3 = fmaf(f[384 + kk], w, acc3);
        }

        const int r0 = half * 4;
        atomicAdd(&lbuf[(r0 + 0) * 8 + k], acc0 * acoef);
        atomicAdd(&lbuf[(r0 + 1) * 8 + k], acc1 * acoef);
        atomicAdd(&lbuf[(r0 + 2) * 8 + k], acc2 * acoef);
        atomicAdd(&lbuf[(r0 + 3) * 8 + k], acc3 * acoef);

        if (STORE_H) {
            if (row0 + r0 + 3 < N) {
                h_out[(size_t)(row0 + r0 + 0) * 128 + col] = acc0;
                h_out[(size_t)(row0 + r0 + 1) * 128 + col] = acc1;
                h_out[(size_t)(row0 + r0 + 2) * 128 + col] = acc2;
                h_out[(size_t)(row0 + r0 + 3) * 128 + col] = acc3;
            } else {
                if (row0 + r0 + 0 < N) h_out[(size_t)(row0 + r0 + 0) * 128 + col] = acc0;
                if (row0 + r0 + 1 < N) h_out[(size_t)(row0 + r0 + 1) * 128 + col] = acc1;
                if (row0 + r0 + 2 < N) h_out[(size_t)(row0 + r0 + 2) * 128 + col] = acc2;
            }
        }
        __syncthreads();
        if (t < 64) {
            const float v = lbuf[t];
            lbuf[t] = 0.f;                      // re-zero for next chunk (pre-barrier safe)
            const int rr = row0 + (t >> 3);
            if (rr < N) logit[(size_t)rr * 8 + (t & 7)] = v;
        }
    }
}

// ---------------------------------------------------------------------------
// Edge pass: one wave (64 lanes) per edge; lane handles 2 of 128 channels.
//   ee   = exp(leakyrelu(el[s][k] + er[d][k]))         (no max-sub: |e| small)
//   esum[d][k]        += ee          (1 lane per head)
//   out [d][c]        += ee * hs[s][c]                  (unnormalized)
// ---------------------------------------------------------------------------
__global__ __launch_bounds__(256) void edge_kernel(
    const int* __restrict__ src_idx,
    const int* __restrict__ dst_idx,
    const float* __restrict__ hs,     // [N_src,128]
    const float* __restrict__ el,     // [N_src,8]
    const float* __restrict__ er,     // [N_dst,8]
    float* __restrict__ out_acc,      // [N_dst,128]
    float* __restrict__ esum,         // [N_dst,8]
    int nEdges)
{
    const int t = threadIdx.x;
    const int lane = t & 63;
    const int e = blockIdx.x * 4 + (t >> 6);
    if (e >= nEdges) return;
    const int s = src_idx[e];
    const int d = dst_idx[e];
    const int c0 = lane << 1;         // even channel; both channels same head
    const int k  = c0 >> 4;

    float x = el[s * 8 + k] + er[d * 8 + k];
    x = (x >= 0.f) ? x : NEG_SLOPE * x;
    const float ee = __expf(x);

    if ((c0 & 15) == 0) unsafeAtomicAdd(&esum[d * 8 + k], ee);

    const float2 h = *(const float2*)(hs + (size_t)s * 128 + c0);
    unsafeAtomicAdd(&out_acc[(size_t)d * 128 + c0],     ee * h.x);
    unsafeAtomicAdd(&out_acc[(size_t)d * 128 + c0 + 1], ee * h.y);
}

// ---------------------------------------------------------------------------
// Normalize: out[d][c] /= esum[d][c/16]  (0 if no incoming edges)
// ---------------------------------------------------------------------------
__global__ __launch_bounds__(256) void norm_kernel(
    float* __restrict__ out, const float* __restrict__ esum, int n)
{
    const int i = blockIdx.x * 256 + threadIdx.x;
    if (i >= n) return;
    const float s = esum[(i >> 7) * 8 + ((i >> 4) & 7)];
    const float v = out[i];
    out[i] = (s > 0.f) ? v / s : 0.f;
}

extern "C" void kernel_launch(void* const* d_in, const int* in_sizes, int n_in,
                              void* d_out, int out_size, void* d_ws, size_t ws_size,
                              hipStream_t stream) {
    const float* feat_src = (const float*)d_in[0];
    const float* feat_dst = (const float*)d_in[1];
    const float* W_src    = (const float*)d_in[2];
    const float* b_src    = (const float*)d_in[3];
    const float* W_dst    = (const float*)d_in[4];
    const float* b_dst    = (const float*)d_in[5];
    const float* attn     = (const float*)d_in[6];
    const int*   src_idx  = (const int*)d_in[7];
    const int*   dst_idx  = (const int*)d_in[8];
    float* out = (float*)d_out;

    const int n_src  = in_sizes[0] / 128;
    const int n_dst  = in_sizes[1] / 128;
    const int nEdges = in_sizes[7];

    // workspace layout
    float* hs   = (float*)d_ws;                       // n_src*128
    float* el   = hs + (size_t)n_src * 128;           // n_src*8
    float* er   = el + (size_t)n_src * 8;             // n_dst*8
    float* esum = er + (size_t)n_dst * 8;             // n_dst*8

    hipMemsetAsync(out,  0, (size_t)n_dst * 128 * sizeof(float), stream);
    hipMemsetAsync(esum, 0, (size_t)n_dst * 8 * sizeof(float), stream);

    proj_kernel<true ><<<1024, 256, 0, stream>>>(feat_src, W_src, b_src, attn, hs, el, n_src, 0);
    proj_kernel<false><<<1024, 256, 0, stream>>>(feat_dst, W_dst, b_dst, attn, nullptr, er, n_dst, 16);

    edge_kernel<<<(nEdges + 3) / 4, 256, 0, stream>>>(src_idx, dst_idx, hs, el, er, out, esum, nEdges);

    const int n_out = n_dst * 128;
    norm_kernel<<<(n_out + 255) / 256, 256, 0, stream>>>(out, esum, n_out);
}

// Round 2
// 729.706 us; speedup vs baseline: 2.2952x; 2.2952x over previous
//
#include <hip/hip_runtime.h>

#define NEG_SLOPE 0.2f

// ---------------------------------------------------------------------------
// Projection: h = feat @ W + b  (128x128), plus per-head logit
//   logit[row][k] = sum_{dd<16} h[row][k*16+dd] * attn[k*32 + attn_off + dd]
// ---------------------------------------------------------------------------
template<bool STORE_H>
__global__ __launch_bounds__(256) void proj_kernel(
    const float* __restrict__ feat,   // [N,128]
    const float* __restrict__ W,      // [128,128]
    const float* __restrict__ b,      // [128]
    const float* __restrict__ attn,   // [8,32]
    float* __restrict__ h_out,        // [N,128] (unused if !STORE_H)
    float* __restrict__ logit,        // [N,8]
    int N, int attn_off)
{
    __shared__ float featl[8 * 128];
    __shared__ float lbuf[64];        // 8 rows x 8 heads
    const int t    = threadIdx.x;
    const int col  = t & 127;
    const int half = t >> 7;          // 0 or 1
    const int k    = col >> 4;
    const float bias  = b[col];
    const float acoef = attn[k * 32 + attn_off + (col & 15)];

    if (t < 64) lbuf[t] = 0.f;

    const int nChunks = (N + 7) >> 3;
    for (int chunk = blockIdx.x; chunk < nChunks; chunk += gridDim.x) {
        const int row0 = chunk << 3;
        {   // stage 8 feat rows (8*128 floats = 256 float4)
            const int r  = t >> 5;
            const int c4 = t & 31;
            const int row = row0 + r;
            float4 v = make_float4(0.f, 0.f, 0.f, 0.f);
            if (row < N) v = ((const float4*)(feat + (size_t)row * 128))[c4];
            ((float4*)featl)[t] = v;
        }
        __syncthreads();

        float acc0 = bias, acc1 = bias, acc2 = bias, acc3 = bias;
        const float* f = featl + half * 4 * 128;
        #pragma unroll 16
        for (int kk = 0; kk < 128; ++kk) {
            const float w = W[kk * 128 + col];      // coalesced, cache-hot
            acc0 = fmaf(f[kk],       w, acc0);
            acc1 = fmaf(f[128 + kk], w, acc1);
            acc2 = fmaf(f[256 + kk], w, acc2);
            acc3 = fmaf(f[384 + kk], w, acc3);
        }

        const int r0 = half * 4;
        atomicAdd(&lbuf[(r0 + 0) * 8 + k], acc0 * acoef);
        atomicAdd(&lbuf[(r0 + 1) * 8 + k], acc1 * acoef);
        atomicAdd(&lbuf[(r0 + 2) * 8 + k], acc2 * acoef);
        atomicAdd(&lbuf[(r0 + 3) * 8 + k], acc3 * acoef);

        if (STORE_H) {
            if (row0 + r0 + 3 < N) {
                h_out[(size_t)(row0 + r0 + 0) * 128 + col] = acc0;
                h_out[(size_t)(row0 + r0 + 1) * 128 + col] = acc1;
                h_out[(size_t)(row0 + r0 + 2) * 128 + col] = acc2;
                h_out[(size_t)(row0 + r0 + 3) * 128 + col] = acc3;
            } else {
                if (row0 + r0 + 0 < N) h_out[(size_t)(row0 + r0 + 0) * 128 + col] = acc0;
                if (row0 + r0 + 1 < N) h_out[(size_t)(row0 + r0 + 1) * 128 + col] = acc1;
                if (row0 + r0 + 2 < N) h_out[(size_t)(row0 + r0 + 2) * 128 + col] = acc2;
            }
        }
        __syncthreads();
        if (t < 64) {
            const float v = lbuf[t];
            lbuf[t] = 0.f;                      // re-zero for next chunk
            const int rr = row0 + (t >> 3);
            if (rr < N) logit[(size_t)rr * 8 + (t & 7)] = v;
        }
    }
}

// ---------------------------------------------------------------------------
// 1) histogram of dst degrees
// ---------------------------------------------------------------------------
__global__ __launch_bounds__(256) void hist_kernel(
    const int* __restrict__ dst_idx, int* __restrict__ cnt, int nEdges)
{
    for (int e = blockIdx.x * 256 + threadIdx.x; e < nEdges; e += gridDim.x * 256)
        atomicAdd(&cnt[dst_idx[e]], 1);
}

// ---------------------------------------------------------------------------
// 2) single-block exclusive scan over n counts -> off[0..n], cur[] = copy
// ---------------------------------------------------------------------------
__global__ __launch_bounds__(1024) void scan_kernel(
    const int* __restrict__ cnt, int* __restrict__ off, int* __restrict__ cur, int n)
{
    __shared__ int buf[1024];
    __shared__ int carry_s;
    const int t = threadIdx.x;
    if (t == 0) carry_s = 0;
    __syncthreads();
    for (int base = 0; base < n; base += 1024) {
        const int i = base + t;
        const int v = (i < n) ? cnt[i] : 0;
        buf[t] = v;
        __syncthreads();
        #pragma unroll
        for (int s = 1; s < 1024; s <<= 1) {
            const int add = (t >= s) ? buf[t - s] : 0;
            __syncthreads();
            buf[t] += add;
            __syncthreads();
        }
        const int incl  = buf[t];
        const int carry = carry_s;
        const int excl  = carry + incl - v;
        if (i < n) { off[i] = excl; cur[i] = excl; }
        __syncthreads();
        if (t == 1023) carry_s = carry + incl;
        __syncthreads();
    }
    if (t == 0) off[n] = carry_s;
}

// ---------------------------------------------------------------------------
// 3) scatter src ids into dst-sorted order
// ---------------------------------------------------------------------------
__global__ __launch_bounds__(256) void scatter_kernel(
    const int* __restrict__ src_idx, const int* __restrict__ dst_idx,
    int* __restrict__ cur, int* __restrict__ sorted_src, int nEdges)
{
    for (int e = blockIdx.x * 256 + threadIdx.x; e < nEdges; e += gridDim.x * 256) {
        const int d = dst_idx[e];
        const int pos = atomicAdd(&cur[d], 1);
        sorted_src[pos] = src_idx[e];
    }
}

// ---------------------------------------------------------------------------
// 4) one wave per dst: register-accumulate softmax-weighted aggregation.
//    lane owns channels {2*lane, 2*lane+1}; head k = lane>>3.
//    esum accumulated redundantly per lane (identical within a head) ->
//    no cross-lane reduction, no atomics.
// ---------------------------------------------------------------------------
__global__ __launch_bounds__(256) void reduce_kernel(
    const int* __restrict__ sorted_src, const int* __restrict__ off,
    const float* __restrict__ hs,     // [N_src,128]
    const float* __restrict__ el,     // [N_src,8]
    const float* __restrict__ er,     // [N_dst,8]
    float* __restrict__ out,          // [N_dst,128]
    int n_dst)
{
    const int wid = blockIdx.x * 4 + (threadIdx.x >> 6);
    if (wid >= n_dst) return;
    const int lane = threadIdx.x & 63;
    const int c0 = lane << 1;
    const int k  = lane >> 3;
    const float erk = er[(size_t)wid * 8 + k];
    const int beg = off[wid], end = off[wid + 1];

    float acc0 = 0.f, acc1 = 0.f, es = 0.f;
    for (int i = beg; i < end; ++i) {
        const int s = sorted_src[i];                       // broadcast load
        float x = el[(size_t)s * 8 + k] + erk;
        x = (x >= 0.f) ? x : NEG_SLOPE * x;
        const float ee = __expf(x);
        es += ee;
        const float2 h = *(const float2*)(hs + (size_t)s * 128 + c0);
        acc0 = fmaf(ee, h.x, acc0);
        acc1 = fmaf(ee, h.y, acc1);
    }
    const float inv = (es > 0.f) ? 1.f / es : 0.f;
    float2 o; o.x = acc0 * inv; o.y = acc1 * inv;
    *(float2*)(out + (size_t)wid * 128 + c0) = o;
}

extern "C" void kernel_launch(void* const* d_in, const int* in_sizes, int n_in,
                              void* d_out, int out_size, void* d_ws, size_t ws_size,
                              hipStream_t stream) {
    const float* feat_src = (const float*)d_in[0];
    const float* feat_dst = (const float*)d_in[1];
    const float* W_src    = (const float*)d_in[2];
    const float* b_src    = (const float*)d_in[3];
    const float* W_dst    = (const float*)d_in[4];
    const float* b_dst    = (const float*)d_in[5];
    const float* attn     = (const float*)d_in[6];
    const int*   src_idx  = (const int*)d_in[7];
    const int*   dst_idx  = (const int*)d_in[8];
    float* out = (float*)d_out;

    const int n_src  = in_sizes[0] / 128;
    const int n_dst  = in_sizes[1] / 128;
    const int nEdges = in_sizes[7];

    // workspace layout (floats/ints, 4B each)
    float* hs         = (float*)d_ws;                       // n_src*128
    float* el         = hs + (size_t)n_src * 128;           // n_src*8
    float* er         = el + (size_t)n_src * 8;             // n_dst*8
    int*   cnt        = (int*)(er + (size_t)n_dst * 8);     // n_dst
    int*   off        = cnt + n_dst;                        // n_dst+1
    int*   cur        = off + n_dst + 1;                    // n_dst
    int*   sorted_src = cur + n_dst;                        // nEdges

    hipMemsetAsync(cnt, 0, (size_t)n_dst * sizeof(int), stream);

    proj_kernel<true ><<<1024, 256, 0, stream>>>(feat_src, W_src, b_src, attn, hs, el, n_src, 0);
    proj_kernel<false><<<1024, 256, 0, stream>>>(feat_dst, W_dst, b_dst, attn, nullptr, er, n_dst, 16);

    hist_kernel<<<1024, 256, 0, stream>>>(dst_idx, cnt, nEdges);
    scan_kernel<<<1, 1024, 0, stream>>>(cnt, off, cur, n_dst);
    scatter_kernel<<<1024, 256, 0, stream>>>(src_idx, dst_idx, cur, sorted_src, nEdges);

    reduce_kernel<<<(n_dst + 3) / 4, 256, 0, stream>>>(sorted_src, off, hs, el, er, out, n_dst);
}

// Round 3
// 575.878 us; speedup vs baseline: 2.9083x; 1.2671x over previous
//
#include <hip/hip_runtime.h>
#include <hip/hip_bf16.h>

#define NEG_SLOPE 0.2f

// ---------------------------------------------------------------------------
// Projection: h = feat @ W + b  (128x128), plus per-head logit
//   logit[row][k] = sum_{dd<16} h[row][k*16+dd] * attn[k*32 + attn_off + dd]
// Block = 256 threads: 128 cols x 2 row-halves; 8 rows/chunk, 4 rows/thread.
// feat staged in LDS, read back as float4 (ds_read_b128, 4x fewer LDS instrs).
// hs stored as bf16 for the gather phase.
// ---------------------------------------------------------------------------
template<bool STORE_H>
__global__ __launch_bounds__(256) void proj_kernel(
    const float* __restrict__ feat,   // [N,128]
    const float* __restrict__ W,      // [128,128]
    const float* __restrict__ b,      // [128]
    const float* __restrict__ attn,   // [8,32]
    __hip_bfloat16* __restrict__ h_out, // [N,128] bf16 (unused if !STORE_H)
    float* __restrict__ logit,        // [N,8]
    int N, int attn_off)
{
    __shared__ float featl[8 * 128];
    __shared__ float lbuf[64];        // 8 rows x 8 heads
    const int t    = threadIdx.x;
    const int col  = t & 127;
    const int half = t >> 7;          // 0 or 1
    const int k    = col >> 4;
    const float bias  = b[col];
    const float acoef = attn[k * 32 + attn_off + (col & 15)];

    if (t < 64) lbuf[t] = 0.f;

    const int nChunks = (N + 7) >> 3;
    for (int chunk = blockIdx.x; chunk < nChunks; chunk += gridDim.x) {
        const int row0 = chunk << 3;
        {   // stage 8 feat rows (8*128 floats = 256 float4)
            const int r  = t >> 5;
            const int c4 = t & 31;
            const int row = row0 + r;
            float4 v = make_float4(0.f, 0.f, 0.f, 0.f);
            if (row < N) v = ((const float4*)(feat + (size_t)row * 128))[c4];
            ((float4*)featl)[t] = v;
        }
        __syncthreads();

        float acc0 = bias, acc1 = bias, acc2 = bias, acc3 = bias;
        const float4* f4 = ((const float4*)featl) + half * 4 * 32;
        #pragma unroll 8
        for (int q = 0; q < 32; ++q) {
            const float4 a0 = f4[q];
            const float4 a1 = f4[32 + q];
            const float4 a2 = f4[64 + q];
            const float4 a3 = f4[96 + q];
            const float* Wq = W + (size_t)(q * 4) * 128 + col;
            const float w0 = Wq[0];
            const float w1 = Wq[128];
            const float w2 = Wq[256];
            const float w3 = Wq[384];
            acc0 = fmaf(a0.x, w0, acc0); acc0 = fmaf(a0.y, w1, acc0);
            acc0 = fmaf(a0.z, w2, acc0); acc0 = fmaf(a0.w, w3, acc0);
            acc1 = fmaf(a1.x, w0, acc1); acc1 = fmaf(a1.y, w1, acc1);
            acc1 = fmaf(a1.z, w2, acc1); acc1 = fmaf(a1.w, w3, acc1);
            acc2 = fmaf(a2.x, w0, acc2); acc2 = fmaf(a2.y, w1, acc2);
            acc2 = fmaf(a2.z, w2, acc2); acc2 = fmaf(a2.w, w3, acc2);
            acc3 = fmaf(a3.x, w0, acc3); acc3 = fmaf(a3.y, w1, acc3);
            acc3 = fmaf(a3.z, w2, acc3); acc3 = fmaf(a3.w, w3, acc3);
        }

        const int r0 = half * 4;
        atomicAdd(&lbuf[(r0 + 0) * 8 + k], acc0 * acoef);
        atomicAdd(&lbuf[(r0 + 1) * 8 + k], acc1 * acoef);
        atomicAdd(&lbuf[(r0 + 2) * 8 + k], acc2 * acoef);
        atomicAdd(&lbuf[(r0 + 3) * 8 + k], acc3 * acoef);

        if (STORE_H) {
            const int rb = row0 + r0;
            if (rb + 3 < N) {
                h_out[(size_t)(rb + 0) * 128 + col] = __float2bfloat16(acc0);
                h_out[(size_t)(rb + 1) * 128 + col] = __float2bfloat16(acc1);
                h_out[(size_t)(rb + 2) * 128 + col] = __float2bfloat16(acc2);
                h_out[(size_t)(rb + 3) * 128 + col] = __float2bfloat16(acc3);
            } else {
                if (rb + 0 < N) h_out[(size_t)(rb + 0) * 128 + col] = __float2bfloat16(acc0);
                if (rb + 1 < N) h_out[(size_t)(rb + 1) * 128 + col] = __float2bfloat16(acc1);
                if (rb + 2 < N) h_out[(size_t)(rb + 2) * 128 + col] = __float2bfloat16(acc2);
            }
        }
        __syncthreads();
        if (t < 64) {
            const float v = lbuf[t];
            lbuf[t] = 0.f;                      // re-zero for next chunk
            const int rr = row0 + (t >> 3);
            if (rr < N) logit[(size_t)rr * 8 + (t & 7)] = v;
        }
    }
}

// ---------------------------------------------------------------------------
// 1) histogram of dst degrees
// ---------------------------------------------------------------------------
__global__ __launch_bounds__(256) void hist_kernel(
    const int* __restrict__ dst_idx, int* __restrict__ cnt, int nEdges)
{
    for (int e = blockIdx.x * 256 + threadIdx.x; e < nEdges; e += gridDim.x * 256)
        atomicAdd(&cnt[dst_idx[e]], 1);
}

// ---------------------------------------------------------------------------
// 2a) partial sums: block b sums cnt[b*1024 .. b*1024+1023] -> part[b]
// ---------------------------------------------------------------------------
__global__ __launch_bounds__(1024) void scan_part_kernel(
    const int* __restrict__ cnt, int* __restrict__ part, int n)
{
    __shared__ int wsum[16];
    const int t = threadIdx.x;
    const int i = blockIdx.x * 1024 + t;
    int v = (i < n) ? cnt[i] : 0;
    #pragma unroll
    for (int s = 32; s > 0; s >>= 1) v += __shfl_down(v, s, 64);
    if ((t & 63) == 0) wsum[t >> 6] = v;
    __syncthreads();
    if (t < 16) {
        int x = wsum[t];
        #pragma unroll
        for (int s = 8; s > 0; s >>= 1) x += __shfl_down(x, s, 64);
        if (t == 0) part[blockIdx.x] = x;
    }
}

// ---------------------------------------------------------------------------
// 2b) single-block exclusive scan of nPart (<=1024) partials, in place;
//     also writes off[n] = total
// ---------------------------------------------------------------------------
__global__ __launch_bounds__(1024) void scan_top_kernel(
    int* __restrict__ part, int* __restrict__ off, int nPart, int n)
{
    __shared__ int buf[1024];
    const int t = threadIdx.x;
    const int v = (t < nPart) ? part[t] : 0;
    buf[t] = v;
    __syncthreads();
    #pragma unroll
    for (int s = 1; s < 1024; s <<= 1) {
        const int add = (t >= s) ? buf[t - s] : 0;
        __syncthreads();
        buf[t] += add;
        __syncthreads();
    }
    if (t < nPart) part[t] = buf[t] - v;        // exclusive
    if (t == 1023) off[n] = buf[1023];          // total
}

// ---------------------------------------------------------------------------
// 2c) per-block local exclusive scan + base -> off, cur
// ---------------------------------------------------------------------------
__global__ __launch_bounds__(1024) void scan_local_kernel(
    const int* __restrict__ cnt, const int* __restrict__ part,
    int* __restrict__ off, int* __restrict__ cur, int n)
{
    __shared__ int buf[1024];
    const int t = threadIdx.x;
    const int i = blockIdx.x * 1024 + t;
    const int v = (i < n) ? cnt[i] : 0;
    buf[t] = v;
    __syncthreads();
    #pragma unroll
    for (int s = 1; s < 1024; s <<= 1) {
        const int add = (t >= s) ? buf[t - s] : 0;
        __syncthreads();
        buf[t] += add;
        __syncthreads();
    }
    if (i < n) {
        const int excl = part[blockIdx.x] + buf[t] - v;
        off[i] = excl;
        cur[i] = excl;
    }
}

// ---------------------------------------------------------------------------
// 3) scatter src ids into dst-sorted order
// ---------------------------------------------------------------------------
__global__ __launch_bounds__(256) void scatter_kernel(
    const int* __restrict__ src_idx, const int* __restrict__ dst_idx,
    int* __restrict__ cur, int* __restrict__ sorted_src, int nEdges)
{
    for (int e = blockIdx.x * 256 + threadIdx.x; e < nEdges; e += gridDim.x * 256) {
        const int d = dst_idx[e];
        const int pos = atomicAdd(&cur[d], 1);
        sorted_src[pos] = src_idx[e];
    }
}

// ---------------------------------------------------------------------------
// 4) one wave per dst: register-accumulate softmax-weighted aggregation.
//    lane owns channels {2*lane, 2*lane+1}; head k = lane>>3.
//    hs is bf16: one 4B load/lane/edge, expanded by bit-shift (exact).
// ---------------------------------------------------------------------------
__global__ __launch_bounds__(256) void reduce_kernel(
    const int* __restrict__ sorted_src, const int* __restrict__ off,
    const __hip_bfloat16* __restrict__ hs, // [N_src,128] bf16
    const float* __restrict__ el,     // [N_src,8]
    const float* __restrict__ er,     // [N_dst,8]
    float* __restrict__ out,          // [N_dst,128]
    int n_dst)
{
    const int wid = blockIdx.x * 4 + (threadIdx.x >> 6);
    if (wid >= n_dst) return;
    const int lane = threadIdx.x & 63;
    const int c0 = lane << 1;
    const int k  = lane >> 3;
    const float erk = er[(size_t)wid * 8 + k];
    const int beg = off[wid], end = off[wid + 1];

    float acc0 = 0.f, acc1 = 0.f, es = 0.f;
    int i = beg;
    for (; i + 2 <= end; i += 2) {
        const int s0 = sorted_src[i];
        const int s1 = sorted_src[i + 1];
        const float l0 = el[(size_t)s0 * 8 + k];
        const float l1 = el[(size_t)s1 * 8 + k];
        const unsigned u0 = ((const unsigned*)(hs + (size_t)s0 * 128))[lane];
        const unsigned u1 = ((const unsigned*)(hs + (size_t)s1 * 128))[lane];
        float x0 = l0 + erk; x0 = (x0 >= 0.f) ? x0 : NEG_SLOPE * x0;
        float x1 = l1 + erk; x1 = (x1 >= 0.f) ? x1 : NEG_SLOPE * x1;
        const float e0 = __expf(x0);
        const float e1 = __expf(x1);
        es += e0 + e1;
        acc0 = fmaf(e0, __uint_as_float(u0 << 16), acc0);
        acc1 = fmaf(e0, __uint_as_float(u0 & 0xffff0000u), acc1);
        acc0 = fmaf(e1, __uint_as_float(u1 << 16), acc0);
        acc1 = fmaf(e1, __uint_as_float(u1 & 0xffff0000u), acc1);
    }
    if (i < end) {
        const int s0 = sorted_src[i];
        const float l0 = el[(size_t)s0 * 8 + k];
        const unsigned u0 = ((const unsigned*)(hs + (size_t)s0 * 128))[lane];
        float x0 = l0 + erk; x0 = (x0 >= 0.f) ? x0 : NEG_SLOPE * x0;
        const float e0 = __expf(x0);
        es += e0;
        acc0 = fmaf(e0, __uint_as_float(u0 << 16), acc0);
        acc1 = fmaf(e0, __uint_as_float(u0 & 0xffff0000u), acc1);
    }
    const float inv = (es > 0.f) ? 1.f / es : 0.f;
    float2 o; o.x = acc0 * inv; o.y = acc1 * inv;
    *(float2*)(out + (size_t)wid * 128 + c0) = o;
}

extern "C" void kernel_launch(void* const* d_in, const int* in_sizes, int n_in,
                              void* d_out, int out_size, void* d_ws, size_t ws_size,
                              hipStream_t stream) {
    const float* feat_src = (const float*)d_in[0];
    const float* feat_dst = (const float*)d_in[1];
    const float* W_src    = (const float*)d_in[2];
    const float* b_src    = (const float*)d_in[3];
    const float* W_dst    = (const float*)d_in[4];
    const float* b_dst    = (const float*)d_in[5];
    const float* attn     = (const float*)d_in[6];
    const int*   src_idx  = (const int*)d_in[7];
    const int*   dst_idx  = (const int*)d_in[8];
    float* out = (float*)d_out;

    const int n_src  = in_sizes[0] / 128;
    const int n_dst  = in_sizes[1] / 128;
    const int nEdges = in_sizes[7];

    // workspace layout (all 16B-aligned)
    __hip_bfloat16* hs = (__hip_bfloat16*)d_ws;            // n_src*128 bf16
    float* el   = (float*)(hs + (size_t)n_src * 128);      // n_src*8
    float* er   = el + (size_t)n_src * 8;                  // n_dst*8
    int*   cnt  = (int*)(er + (size_t)n_dst * 8);          // n_dst
    int*   off  = cnt + n_dst;                             // n_dst+1
    int*   cur  = off + n_dst + 4;                         // n_dst
    int*   part = cur + n_dst;                             // <=1024
    int*   sorted_src = part + 1024;                       // nEdges

    const int nPart = (n_dst + 1023) / 1024;

    hipMemsetAsync(cnt, 0, (size_t)n_dst * sizeof(int), stream);

    proj_kernel<true ><<<1024, 256, 0, stream>>>(feat_src, W_src, b_src, attn, hs, el, n_src, 0);
    proj_kernel<false><<<1024, 256, 0, stream>>>(feat_dst, W_dst, b_dst, attn, nullptr, er, n_dst, 16);

    hist_kernel<<<1024, 256, 0, stream>>>(dst_idx, cnt, nEdges);
    scan_part_kernel<<<nPart, 1024, 0, stream>>>(cnt, part, n_dst);
    scan_top_kernel<<<1, 1024, 0, stream>>>(part, off, nPart, n_dst);
    scan_local_kernel<<<nPart, 1024, 0, stream>>>(cnt, part, off, cur, n_dst);
    scatter_kernel<<<1024, 256, 0, stream>>>(src_idx, dst_idx, cur, sorted_src, nEdges);

    reduce_kernel<<<(n_dst + 3) / 4, 256, 0, stream>>>(sorted_src, off, hs, el, er, out, n_dst);
}

// Round 4
// 443.665 us; speedup vs baseline: 3.7750x; 1.2980x over previous
//
#include <hip/hip_runtime.h>
#include <hip/hip_bf16.h>

#define NEG_SLOPE 0.2f

__device__ __forceinline__ float b2f_lo(unsigned u) { return __uint_as_float(u << 16); }
__device__ __forceinline__ float b2f_hi(unsigned u) { return __uint_as_float(u & 0xffff0000u); }

// ---------------------------------------------------------------------------
// Projection: h = feat @ W + b  (128x128), plus per-head logit
// ---------------------------------------------------------------------------
template<bool STORE_H>
__global__ __launch_bounds__(256) void proj_kernel(
    const float* __restrict__ feat,   // [N,128]
    const float* __restrict__ W,      // [128,128]
    const float* __restrict__ b,      // [128]
    const float* __restrict__ attn,   // [8,32]
    __hip_bfloat16* __restrict__ h_out, // [N,128] bf16 (unused if !STORE_H)
    float* __restrict__ logit,        // [N,8]
    int N, int attn_off)
{
    __shared__ float featl[8 * 128];
    __shared__ float lbuf[64];        // 8 rows x 8 heads
    const int t    = threadIdx.x;
    const int col  = t & 127;
    const int half = t >> 7;          // 0 or 1
    const int k    = col >> 4;
    const float bias  = b[col];
    const float acoef = attn[k * 32 + attn_off + (col & 15)];

    if (t < 64) lbuf[t] = 0.f;

    const int nChunks = (N + 7) >> 3;
    for (int chunk = blockIdx.x; chunk < nChunks; chunk += gridDim.x) {
        const int row0 = chunk << 3;
        {   // stage 8 feat rows (8*128 floats = 256 float4)
            const int r  = t >> 5;
            const int c4 = t & 31;
            const int row = row0 + r;
            float4 v = make_float4(0.f, 0.f, 0.f, 0.f);
            if (row < N) v = ((const float4*)(feat + (size_t)row * 128))[c4];
            ((float4*)featl)[t] = v;
        }
        __syncthreads();

        float acc0 = bias, acc1 = bias, acc2 = bias, acc3 = bias;
        const float4* f4 = ((const float4*)featl) + half * 4 * 32;
        #pragma unroll 8
        for (int q = 0; q < 32; ++q) {
            const float4 a0 = f4[q];
            const float4 a1 = f4[32 + q];
            const float4 a2 = f4[64 + q];
            const float4 a3 = f4[96 + q];
            const float* Wq = W + (size_t)(q * 4) * 128 + col;
            const float w0 = Wq[0];
            const float w1 = Wq[128];
            const float w2 = Wq[256];
            const float w3 = Wq[384];
            acc0 = fmaf(a0.x, w0, acc0); acc0 = fmaf(a0.y, w1, acc0);
            acc0 = fmaf(a0.z, w2, acc0); acc0 = fmaf(a0.w, w3, acc0);
            acc1 = fmaf(a1.x, w0, acc1); acc1 = fmaf(a1.y, w1, acc1);
            acc1 = fmaf(a1.z, w2, acc1); acc1 = fmaf(a1.w, w3, acc1);
            acc2 = fmaf(a2.x, w0, acc2); acc2 = fmaf(a2.y, w1, acc2);
            acc2 = fmaf(a2.z, w2, acc2); acc2 = fmaf(a2.w, w3, acc2);
            acc3 = fmaf(a3.x, w0, acc3); acc3 = fmaf(a3.y, w1, acc3);
            acc3 = fmaf(a3.z, w2, acc3); acc3 = fmaf(a3.w, w3, acc3);
        }

        const int r0 = half * 4;
        atomicAdd(&lbuf[(r0 + 0) * 8 + k], acc0 * acoef);
        atomicAdd(&lbuf[(r0 + 1) * 8 + k], acc1 * acoef);
        atomicAdd(&lbuf[(r0 + 2) * 8 + k], acc2 * acoef);
        atomicAdd(&lbuf[(r0 + 3) * 8 + k], acc3 * acoef);

        if (STORE_H) {
            const int rb = row0 + r0;
            if (rb + 3 < N) {
                h_out[(size_t)(rb + 0) * 128 + col] = __float2bfloat16(acc0);
                h_out[(size_t)(rb + 1) * 128 + col] = __float2bfloat16(acc1);
                h_out[(size_t)(rb + 2) * 128 + col] = __float2bfloat16(acc2);
                h_out[(size_t)(rb + 3) * 128 + col] = __float2bfloat16(acc3);
            } else {
                if (rb + 0 < N) h_out[(size_t)(rb + 0) * 128 + col] = __float2bfloat16(acc0);
                if (rb + 1 < N) h_out[(size_t)(rb + 1) * 128 + col] = __float2bfloat16(acc1);
                if (rb + 2 < N) h_out[(size_t)(rb + 2) * 128 + col] = __float2bfloat16(acc2);
            }
        }
        __syncthreads();
        if (t < 64) {
            const float v = lbuf[t];
            lbuf[t] = 0.f;                      // re-zero for next chunk
            const int rr = row0 + (t >> 3);
            if (rr < N) logit[(size_t)rr * 8 + (t & 7)] = v;
        }
    }
}

// ---------------------------------------------------------------------------
// 1) fused histogram + rank: rank[e] = arrival order among edges of dst[e].
//    8 edges/thread -> 8 outstanding returning atomics (latency amortized).
// ---------------------------------------------------------------------------
__global__ __launch_bounds__(256) void rank_hist_kernel(
    const int* __restrict__ dst_idx, int* __restrict__ cnt,
    int* __restrict__ rank, int nEdges)
{
    const int base = (blockIdx.x * 256 + threadIdx.x) * 8;
    if (base + 8 <= nEdges) {
        const int4 d0 = *(const int4*)(dst_idx + base);
        const int4 d1 = *(const int4*)(dst_idx + base + 4);
        int4 r0, r1;
        r0.x = atomicAdd(&cnt[d0.x], 1);
        r0.y = atomicAdd(&cnt[d0.y], 1);
        r0.z = atomicAdd(&cnt[d0.z], 1);
        r0.w = atomicAdd(&cnt[d0.w], 1);
        r1.x = atomicAdd(&cnt[d1.x], 1);
        r1.y = atomicAdd(&cnt[d1.y], 1);
        r1.z = atomicAdd(&cnt[d1.z], 1);
        r1.w = atomicAdd(&cnt[d1.w], 1);
        *(int4*)(rank + base)     = r0;
        *(int4*)(rank + base + 4) = r1;
    } else {
        for (int e = base; e < nEdges; ++e)
            rank[e] = atomicAdd(&cnt[dst_idx[e]], 1);
    }
}

// ---------------------------------------------------------------------------
// 2a) partial sums per 1024-block
// ---------------------------------------------------------------------------
__global__ __launch_bounds__(1024) void scan_part_kernel(
    const int* __restrict__ cnt, int* __restrict__ part, int n)
{
    __shared__ int wsum[16];
    const int t = threadIdx.x;
    const int i = blockIdx.x * 1024 + t;
    int v = (i < n) ? cnt[i] : 0;
    #pragma unroll
    for (int s = 32; s > 0; s >>= 1) v += __shfl_down(v, s, 64);
    if ((t & 63) == 0) wsum[t >> 6] = v;
    __syncthreads();
    if (t < 16) {
        int x = wsum[t];
        #pragma unroll
        for (int s = 8; s > 0; s >>= 1) x += __shfl_down(x, s, 64);
        if (t == 0) part[blockIdx.x] = x;
    }
}

// ---------------------------------------------------------------------------
// 2b) single-block exclusive scan of nPart partials; off[n] = total
// ---------------------------------------------------------------------------
__global__ __launch_bounds__(1024) void scan_top_kernel(
    int* __restrict__ part, int* __restrict__ off, int nPart, int n)
{
    __shared__ int buf[1024];
    const int t = threadIdx.x;
    const int v = (t < nPart) ? part[t] : 0;
    buf[t] = v;
    __syncthreads();
    #pragma unroll
    for (int s = 1; s < 1024; s <<= 1) {
        const int add = (t >= s) ? buf[t - s] : 0;
        __syncthreads();
        buf[t] += add;
        __syncthreads();
    }
    if (t < nPart) part[t] = buf[t] - v;        // exclusive
    if (t == 1023) off[n] = buf[1023];          // total
}

// ---------------------------------------------------------------------------
// 2c) per-block local exclusive scan + base -> off
// ---------------------------------------------------------------------------
__global__ __launch_bounds__(1024) void scan_local_kernel(
    const int* __restrict__ cnt, const int* __restrict__ part,
    int* __restrict__ off, int n)
{
    __shared__ int buf[1024];
    const int t = threadIdx.x;
    const int i = blockIdx.x * 1024 + t;
    const int v = (i < n) ? cnt[i] : 0;
    buf[t] = v;
    __syncthreads();
    #pragma unroll
    for (int s = 1; s < 1024; s <<= 1) {
        const int add = (t >= s) ? buf[t - s] : 0;
        __syncthreads();
        buf[t] += add;
        __syncthreads();
    }
    if (i < n) off[i] = part[blockIdx.x] + buf[t] - v;
}

// ---------------------------------------------------------------------------
// 3) deterministic scatter: pos = off[d] + rank[e]. NO atomics; stores are
//    fire-and-forget and fully pipelined.
// ---------------------------------------------------------------------------
__global__ __launch_bounds__(256) void scatter_kernel(
    const int* __restrict__ src_idx, const int* __restrict__ dst_idx,
    const int* __restrict__ rank, const int* __restrict__ off,
    int* __restrict__ sorted_src, int nEdges)
{
    const int base = (blockIdx.x * 256 + threadIdx.x) * 8;
    if (base + 8 <= nEdges) {
        const int4 d0 = *(const int4*)(dst_idx + base);
        const int4 d1 = *(const int4*)(dst_idx + base + 4);
        const int4 r0 = *(const int4*)(rank + base);
        const int4 r1 = *(const int4*)(rank + base + 4);
        const int4 s0 = *(const int4*)(src_idx + base);
        const int4 s1 = *(const int4*)(src_idx + base + 4);
        sorted_src[off[d0.x] + r0.x] = s0.x;
        sorted_src[off[d0.y] + r0.y] = s0.y;
        sorted_src[off[d0.z] + r0.z] = s0.z;
        sorted_src[off[d0.w] + r0.w] = s0.w;
        sorted_src[off[d1.x] + r1.x] = s1.x;
        sorted_src[off[d1.y] + r1.y] = s1.y;
        sorted_src[off[d1.z] + r1.z] = s1.z;
        sorted_src[off[d1.w] + r1.w] = s1.w;
    } else {
        for (int e = base; e < nEdges; ++e)
            sorted_src[off[dst_idx[e]] + rank[e]] = src_idx[e];
    }
}

// ---------------------------------------------------------------------------
// 4) one wave per dst, HALF-WAVE per edge: lanes 0-31 do even edges, 32-63
//    odd edges of the same dst. Lane owns 4 channels (uint2 bf16 load).
//    Manual x2 unroll -> 4 gather chains in flight per wave.
// ---------------------------------------------------------------------------
__global__ __launch_bounds__(256) void reduce_kernel(
    const int* __restrict__ sorted_src, const int* __restrict__ off,
    const __hip_bfloat16* __restrict__ hs, // [N_src,128] bf16
    const float* __restrict__ el,     // [N_src,8]
    const float* __restrict__ er,     // [N_dst,8]
    float* __restrict__ out,          // [N_dst,128]
    int n_dst)
{
    const int wid = blockIdx.x * 4 + (threadIdx.x >> 6);
    if (wid >= n_dst) return;
    const int lane = threadIdx.x & 63;
    const int sub  = lane >> 5;       // which edge of the pair
    const int l32  = lane & 31;       // channel group: 4*l32 .. 4*l32+3
    const int k    = l32 >> 2;        // head
    const float erk = er[(size_t)wid * 8 + k];
    const int beg = off[wid], end = off[wid + 1];

    float a0 = 0.f, a1 = 0.f, a2 = 0.f, a3 = 0.f, es = 0.f;
    int i = beg + sub;
    for (; i + 2 < end; i += 4) {     // edges i and i+2 for this half
        const int sA = sorted_src[i];
        const int sB = sorted_src[i + 2];
        const float lA = el[(size_t)sA * 8 + k];
        const float lB = el[(size_t)sB * 8 + k];
        const uint2 uA = ((const uint2*)(hs + (size_t)sA * 128))[l32];
        const uint2 uB = ((const uint2*)(hs + (size_t)sB * 128))[l32];
        float xA = lA + erk; xA = (xA >= 0.f) ? xA : NEG_SLOPE * xA;
        float xB = lB + erk; xB = (xB >= 0.f) ? xB : NEG_SLOPE * xB;
        const float eA = __expf(xA);
        const float eB = __expf(xB);
        es += eA + eB;
        a0 = fmaf(eA, b2f_lo(uA.x), a0); a1 = fmaf(eA, b2f_hi(uA.x), a1);
        a2 = fmaf(eA, b2f_lo(uA.y), a2); a3 = fmaf(eA, b2f_hi(uA.y), a3);
        a0 = fmaf(eB, b2f_lo(uB.x), a0); a1 = fmaf(eB, b2f_hi(uB.x), a1);
        a2 = fmaf(eB, b2f_lo(uB.y), a2); a3 = fmaf(eB, b2f_hi(uB.y), a3);
    }
    for (; i < end; i += 2) {
        const int s = sorted_src[i];
        const float l = el[(size_t)s * 8 + k];
        const uint2 u = ((const uint2*)(hs + (size_t)s * 128))[l32];
        float x = l + erk; x = (x >= 0.f) ? x : NEG_SLOPE * x;
        const float ee = __expf(x);
        es += ee;
        a0 = fmaf(ee, b2f_lo(u.x), a0); a1 = fmaf(ee, b2f_hi(u.x), a1);
        a2 = fmaf(ee, b2f_lo(u.y), a2); a3 = fmaf(ee, b2f_hi(u.y), a3);
    }
    // combine the two halves (channel sets match lane<->lane+32)
    es += __shfl_xor(es, 32);
    a0 += __shfl_xor(a0, 32);
    a1 += __shfl_xor(a1, 32);
    a2 += __shfl_xor(a2, 32);
    a3 += __shfl_xor(a3, 32);
    if (sub == 0) {
        const float inv = (es > 0.f) ? 1.f / es : 0.f;
        float4 o;
        o.x = a0 * inv; o.y = a1 * inv; o.z = a2 * inv; o.w = a3 * inv;
        *(float4*)(out + (size_t)wid * 128 + l32 * 4) = o;
    }
}

extern "C" void kernel_launch(void* const* d_in, const int* in_sizes, int n_in,
                              void* d_out, int out_size, void* d_ws, size_t ws_size,
                              hipStream_t stream) {
    const float* feat_src = (const float*)d_in[0];
    const float* feat_dst = (const float*)d_in[1];
    const float* W_src    = (const float*)d_in[2];
    const float* b_src    = (const float*)d_in[3];
    const float* W_dst    = (const float*)d_in[4];
    const float* b_dst    = (const float*)d_in[5];
    const float* attn     = (const float*)d_in[6];
    const int*   src_idx  = (const int*)d_in[7];
    const int*   dst_idx  = (const int*)d_in[8];
    float* out = (float*)d_out;

    const int n_src  = in_sizes[0] / 128;
    const int n_dst  = in_sizes[1] / 128;
    const int nEdges = in_sizes[7];

    // workspace layout (16B-aligned pieces)
    __hip_bfloat16* hs = (__hip_bfloat16*)d_ws;            // n_src*128 bf16
    float* el   = (float*)(hs + (size_t)n_src * 128);      // n_src*8
    float* er   = el + (size_t)n_src * 8;                  // n_dst*8
    int*   cnt  = (int*)(er + (size_t)n_dst * 8);          // n_dst
    int*   off  = cnt + n_dst;                             // n_dst+1 (+pad)
    int*   part = off + n_dst + 4;                         // <=1024
    int*   rank = part + 1024;                             // nEdges
    int*   sorted_src = rank + nEdges;                     // nEdges

    const int nPart = (n_dst + 1023) / 1024;
    const int eb    = (nEdges + 2047) / 2048;              // 8 edges/thread

    hipMemsetAsync(cnt, 0, (size_t)n_dst * sizeof(int), stream);

    proj_kernel<true ><<<1024, 256, 0, stream>>>(feat_src, W_src, b_src, attn, hs, el, n_src, 0);
    proj_kernel<false><<<1024, 256, 0, stream>>>(feat_dst, W_dst, b_dst, attn, nullptr, er, n_dst, 16);

    rank_hist_kernel<<<eb, 256, 0, stream>>>(dst_idx, cnt, rank, nEdges);
    scan_part_kernel<<<nPart, 1024, 0, stream>>>(cnt, part, n_dst);
    scan_top_kernel<<<1, 1024, 0, stream>>>(part, off, nPart, n_dst);
    scan_local_kernel<<<nPart, 1024, 0, stream>>>(cnt, part, off, n_dst);
    scatter_kernel<<<eb, 256, 0, stream>>>(src_idx, dst_idx, rank, off, sorted_src, nEdges);

    reduce_kernel<<<(n_dst + 3) / 4, 256, 0, stream>>>(sorted_src, off, hs, el, er, out, n_dst);
}

// Round 5
// 306.046 us; speedup vs baseline: 5.4725x; 1.4497x over previous
//
#include <hip/hip_runtime.h>
#include <hip/hip_bf16.h>

#define NEG_SLOPE 0.2f

typedef __attribute__((ext_vector_type(8))) short bf16x8;
typedef __attribute__((ext_vector_type(4))) float f32x4;

__device__ __forceinline__ float b2f_lo(unsigned u) { return __uint_as_float(u << 16); }
__device__ __forceinline__ float b2f_hi(unsigned u) { return __uint_as_float(u & 0xffff0000u); }

// fp32 -> bf16 bits, round-to-nearest-even (matches __float2bfloat16 for normals)
__device__ __forceinline__ short f2b(float x) {
    unsigned u = __float_as_uint(x);
    unsigned r = (u + 0x7fffu + ((u >> 16) & 1u)) >> 16;
    return (short)r;
}

// ---------------------------------------------------------------------------
// 0) Pack W_src/W_dst into MFMA B-fragment order (bf16), plus the fused
//    logit matrices V = W·A' (n-tile 8, cols 0..7 = heads, 8..15 = zero)
//    and c[16] = b·A' (src heads 0..7, dst heads 8..15).
//    Fragment set s, lane l holds B[k=(l>>4)*8 + j + (s&3)*32][n-tile cols],
//    8 consecutive k as 8 bf16 = 16B at wp[s*64 + l].
//    Sets 0..31: s = t*4+q (W col-tile t, k-chunk q). Sets 32..35: V, q=s-32.
// ---------------------------------------------------------------------------
__global__ __launch_bounds__(256) void pack_kernel(
    const float* __restrict__ W_src, const float* __restrict__ W_dst,
    const float* __restrict__ b_src, const float* __restrict__ b_dst,
    const float* __restrict__ attn,  // [8,32]
    uint4* __restrict__ wp_src, uint4* __restrict__ wp_dst,
    float* __restrict__ c_all)       // [16]
{
    const int e = blockIdx.x * 256 + threadIdx.x;
    if (e < 4608) {
        const int which = e / 2304;
        const int e2 = e % 2304;
        const float* W = which ? W_dst : W_src;
        uint4* wp = which ? wp_dst : wp_src;
        const int aoff = which ? 16 : 0;
        short out[8];
        if (e2 < 2048) {                    // W tiles
            const int t = e2 >> 8, q = (e2 >> 6) & 3, l = e2 & 63;
            const int kbase = (l >> 4) * 8 + q * 32;
            const int n = t * 16 + (l & 15);
            #pragma unroll
            for (int j = 0; j < 8; ++j) out[j] = f2b(W[(size_t)(kbase + j) * 128 + n]);
            *(uint4*)&wp[(t * 4 + q) * 64 + l] = *(uint4*)out;
        } else {                            // V tile (fused logits)
            const int e3 = e2 - 2048;
            const int q = e3 >> 6, l = e3 & 63;
            const int kbase = (l >> 4) * 8 + q * 32;
            const int n = l & 15;
            #pragma unroll
            for (int j = 0; j < 8; ++j) {
                float v = 0.f;
                if (n < 8) {
                    for (int dd = 0; dd < 16; ++dd)
                        v += W[(size_t)(kbase + j) * 128 + n * 16 + dd] * attn[n * 32 + aoff + dd];
                }
                out[j] = f2b(v);
            }
            *(uint4*)&wp[(32 + q) * 64 + l] = *(uint4*)out;
        }
    } else if (e < 4624) {                  // c = b·A'
        const int k = e - 4608;
        const int which = k >> 3, kk = k & 7;
        const float* bb = which ? b_dst : b_src;
        const int aoff = which ? 16 : 0;
        float v = 0.f;
        for (int dd = 0; dd < 16; ++dd) v += bb[kk * 16 + dd] * attn[kk * 32 + aoff + dd];
        c_all[k] = v;
    }
}

// ---------------------------------------------------------------------------
// 1) MFMA projection: h = feat·W + b (bf16 inputs, fp32 acc), fused logit
//    via 9th n-tile. Wave handles 2 m-tiles (32 rows); block = 4 waves =
//    128 rows. A-frags straight from global (32B/lane, lines fully used).
// ---------------------------------------------------------------------------
template<bool STORE_H>
__global__ __launch_bounds__(256, 2) void mfma_proj_kernel(
    const float* __restrict__ feat,   // [N,128]
    const uint4* __restrict__ wp,     // 36 fragment sets
    const float* __restrict__ b,      // [128]
    const float* __restrict__ cvec,   // [8]
    short* __restrict__ hs_out,       // [N,128] bf16 bits (unused if !STORE_H)
    float* __restrict__ el_out,       // [N,8]
    int N)
{
    const int t = threadIdx.x;
    const int lane = t & 63;
    const int w = t >> 6;
    const int m  = lane & 15;
    const int q8 = lane >> 4;
    const int row0 = blockIdx.x * 128 + w * 32;   // wave's 32 rows

    f32x4 acc0[9], acc1[9];
    #pragma unroll
    for (int tt = 0; tt < 8; ++tt) {
        const float bn = b[tt * 16 + m];
        acc0[tt] = (f32x4){bn, bn, bn, bn};
        acc1[tt] = (f32x4){bn, bn, bn, bn};
    }
    acc0[8] = (f32x4){0.f, 0.f, 0.f, 0.f};
    acc1[8] = (f32x4){0.f, 0.f, 0.f, 0.f};

    int rowA0 = row0 + m;      if (rowA0 >= N) rowA0 = N - 1;
    int rowA1 = row0 + 16 + m; if (rowA1 >= N) rowA1 = N - 1;
    const float* f0 = feat + (size_t)rowA0 * 128 + q8 * 8;
    const float* f1 = feat + (size_t)rowA1 * 128 + q8 * 8;
    const bf16x8* wpv = (const bf16x8*)wp;

    #pragma unroll
    for (int kc = 0; kc < 4; ++kc) {
        const float4 fa0 = *(const float4*)(f0 + kc * 32);
        const float4 fb0 = *(const float4*)(f0 + kc * 32 + 4);
        const float4 fa1 = *(const float4*)(f1 + kc * 32);
        const float4 fb1 = *(const float4*)(f1 + kc * 32 + 4);
        bf16x8 a0, a1;
        a0[0]=f2b(fa0.x); a0[1]=f2b(fa0.y); a0[2]=f2b(fa0.z); a0[3]=f2b(fa0.w);
        a0[4]=f2b(fb0.x); a0[5]=f2b(fb0.y); a0[6]=f2b(fb0.z); a0[7]=f2b(fb0.w);
        a1[0]=f2b(fa1.x); a1[1]=f2b(fa1.y); a1[2]=f2b(fa1.z); a1[3]=f2b(fa1.w);
        a1[4]=f2b(fb1.x); a1[5]=f2b(fb1.y); a1[6]=f2b(fb1.z); a1[7]=f2b(fb1.w);
        #pragma unroll
        for (int tt = 0; tt < 8; ++tt) {
            const bf16x8 bf = wpv[(tt * 4 + kc) * 64 + lane];
            acc0[tt] = __builtin_amdgcn_mfma_f32_16x16x32_bf16(a0, bf, acc0[tt], 0, 0, 0);
            acc1[tt] = __builtin_amdgcn_mfma_f32_16x16x32_bf16(a1, bf, acc1[tt], 0, 0, 0);
        }
        {
            const bf16x8 bv = wpv[(32 + kc) * 64 + lane];
            acc0[8] = __builtin_amdgcn_mfma_f32_16x16x32_bf16(a0, bv, acc0[8], 0, 0, 0);
            acc1[8] = __builtin_amdgcn_mfma_f32_16x16x32_bf16(a1, bv, acc1[8], 0, 0, 0);
        }
    }

    // epilogue: C/D layout col=lane&15, row=(lane>>4)*4+reg
    #pragma unroll
    for (int half = 0; half < 2; ++half) {
        const f32x4* acc = half ? acc1 : acc0;
        const int rbase = row0 + half * 16 + q8 * 4;
        #pragma unroll
        for (int reg = 0; reg < 4; ++reg) {
            const int row = rbase + reg;
            if (row < N) {
                if (STORE_H) {
                    #pragma unroll
                    for (int tt = 0; tt < 8; ++tt)
                        hs_out[(size_t)row * 128 + tt * 16 + m] = f2b(acc[tt][reg]);
                }
                if (m < 8) el_out[(size_t)row * 8 + m] = acc[8][reg] + cvec[m];
            }
        }
    }
}

// ---------------------------------------------------------------------------
// 2) fused histogram + rank
// ---------------------------------------------------------------------------
__global__ __launch_bounds__(256) void rank_hist_kernel(
    const int* __restrict__ dst_idx, int* __restrict__ cnt,
    int* __restrict__ rank, int nEdges)
{
    const int base = (blockIdx.x * 256 + threadIdx.x) * 8;
    if (base + 8 <= nEdges) {
        const int4 d0 = *(const int4*)(dst_idx + base);
        const int4 d1 = *(const int4*)(dst_idx + base + 4);
        int4 r0, r1;
        r0.x = atomicAdd(&cnt[d0.x], 1);
        r0.y = atomicAdd(&cnt[d0.y], 1);
        r0.z = atomicAdd(&cnt[d0.z], 1);
        r0.w = atomicAdd(&cnt[d0.w], 1);
        r1.x = atomicAdd(&cnt[d1.x], 1);
        r1.y = atomicAdd(&cnt[d1.y], 1);
        r1.z = atomicAdd(&cnt[d1.z], 1);
        r1.w = atomicAdd(&cnt[d1.w], 1);
        *(int4*)(rank + base)     = r0;
        *(int4*)(rank + base + 4) = r1;
    } else {
        for (int e = base; e < nEdges; ++e)
            rank[e] = atomicAdd(&cnt[dst_idx[e]], 1);
    }
}

// ---------------------------------------------------------------------------
// 3a) partial sums per 1024-block
// ---------------------------------------------------------------------------
__global__ __launch_bounds__(1024) void scan_part_kernel(
    const int* __restrict__ cnt, int* __restrict__ part, int n)
{
    __shared__ int wsum[16];
    const int t = threadIdx.x;
    const int i = blockIdx.x * 1024 + t;
    int v = (i < n) ? cnt[i] : 0;
    #pragma unroll
    for (int s = 32; s > 0; s >>= 1) v += __shfl_down(v, s, 64);
    if ((t & 63) == 0) wsum[t >> 6] = v;
    __syncthreads();
    if (t < 16) {
        int x = wsum[t];
        #pragma unroll
        for (int s = 8; s > 0; s >>= 1) x += __shfl_down(x, s, 64);
        if (t == 0) part[blockIdx.x] = x;
    }
}

// ---------------------------------------------------------------------------
// 3b) single-block exclusive scan of partials; off[n] = total
// ---------------------------------------------------------------------------
__global__ __launch_bounds__(1024) void scan_top_kernel(
    int* __restrict__ part, int* __restrict__ off, int nPart, int n)
{
    __shared__ int buf[1024];
    const int t = threadIdx.x;
    const int v = (t < nPart) ? part[t] : 0;
    buf[t] = v;
    __syncthreads();
    #pragma unroll
    for (int s = 1; s < 1024; s <<= 1) {
        const int add = (t >= s) ? buf[t - s] : 0;
        __syncthreads();
        buf[t] += add;
        __syncthreads();
    }
    if (t < nPart) part[t] = buf[t] - v;        // exclusive
    if (t == 1023) off[n] = buf[1023];          // total
}

// ---------------------------------------------------------------------------
// 3c) per-block local exclusive scan + base -> off
// ---------------------------------------------------------------------------
__global__ __launch_bounds__(1024) void scan_local_kernel(
    const int* __restrict__ cnt, const int* __restrict__ part,
    int* __restrict__ off, int n)
{
    __shared__ int buf[1024];
    const int t = threadIdx.x;
    const int i = blockIdx.x * 1024 + t;
    const int v = (i < n) ? cnt[i] : 0;
    buf[t] = v;
    __syncthreads();
    #pragma unroll
    for (int s = 1; s < 1024; s <<= 1) {
        const int add = (t >= s) ? buf[t - s] : 0;
        __syncthreads();
        buf[t] += add;
        __syncthreads();
    }
    if (i < n) off[i] = part[blockIdx.x] + buf[t] - v;
}

// ---------------------------------------------------------------------------
// 4) deterministic scatter: pos = off[d] + rank[e]. No atomics.
// ---------------------------------------------------------------------------
__global__ __launch_bounds__(256) void scatter_kernel(
    const int* __restrict__ src_idx, const int* __restrict__ dst_idx,
    const int* __restrict__ rank, const int* __restrict__ off,
    int* __restrict__ sorted_src, int nEdges)
{
    const int base = (blockIdx.x * 256 + threadIdx.x) * 8;
    if (base + 8 <= nEdges) {
        const int4 d0 = *(const int4*)(dst_idx + base);
        const int4 d1 = *(const int4*)(dst_idx + base + 4);
        const int4 r0 = *(const int4*)(rank + base);
        const int4 r1 = *(const int4*)(rank + base + 4);
        const int4 s0 = *(const int4*)(src_idx + base);
        const int4 s1 = *(const int4*)(src_idx + base + 4);
        sorted_src[off[d0.x] + r0.x] = s0.x;
        sorted_src[off[d0.y] + r0.y] = s0.y;
        sorted_src[off[d0.z] + r0.z] = s0.z;
        sorted_src[off[d0.w] + r0.w] = s0.w;
        sorted_src[off[d1.x] + r1.x] = s1.x;
        sorted_src[off[d1.y] + r1.y] = s1.y;
        sorted_src[off[d1.z] + r1.z] = s1.z;
        sorted_src[off[d1.w] + r1.w] = s1.w;
    } else {
        for (int e = base; e < nEdges; ++e)
            sorted_src[off[dst_idx[e]] + rank[e]] = src_idx[e];
    }
}

// ---------------------------------------------------------------------------
// 5) one wave per dst, half-wave per edge, register softmax-aggregation.
// ---------------------------------------------------------------------------
__global__ __launch_bounds__(256) void reduce_kernel(
    const int* __restrict__ sorted_src, const int* __restrict__ off,
    const __hip_bfloat16* __restrict__ hs, // [N_src,128] bf16
    const float* __restrict__ el,     // [N_src,8]
    const float* __restrict__ er,     // [N_dst,8]
    float* __restrict__ out,          // [N_dst,128]
    int n_dst)
{
    const int wid = blockIdx.x * 4 + (threadIdx.x >> 6);
    if (wid >= n_dst) return;
    const int lane = threadIdx.x & 63;
    const int sub  = lane >> 5;
    const int l32  = lane & 31;
    const int k    = l32 >> 2;
    const float erk = er[(size_t)wid * 8 + k];
    const int beg = off[wid], end = off[wid + 1];

    float a0 = 0.f, a1 = 0.f, a2 = 0.f, a3 = 0.f, es = 0.f;
    int i = beg + sub;
    for (; i + 2 < end; i += 4) {
        const int sA = sorted_src[i];
        const int sB = sorted_src[i + 2];
        const float lA = el[(size_t)sA * 8 + k];
        const float lB = el[(size_t)sB * 8 + k];
        const uint2 uA = ((const uint2*)(hs + (size_t)sA * 128))[l32];
        const uint2 uB = ((const uint2*)(hs + (size_t)sB * 128))[l32];
        float xA = lA + erk; xA = (xA >= 0.f) ? xA : NEG_SLOPE * xA;
        float xB = lB + erk; xB = (xB >= 0.f) ? xB : NEG_SLOPE * xB;
        const float eA = __expf(xA);
        const float eB = __expf(xB);
        es += eA + eB;
        a0 = fmaf(eA, b2f_lo(uA.x), a0); a1 = fmaf(eA, b2f_hi(uA.x), a1);
        a2 = fmaf(eA, b2f_lo(uA.y), a2); a3 = fmaf(eA, b2f_hi(uA.y), a3);
        a0 = fmaf(eB, b2f_lo(uB.x), a0); a1 = fmaf(eB, b2f_hi(uB.x), a1);
        a2 = fmaf(eB, b2f_lo(uB.y), a2); a3 = fmaf(eB, b2f_hi(uB.y), a3);
    }
    for (; i < end; i += 2) {
        const int s = sorted_src[i];
        const float l = el[(size_t)s * 8 + k];
        const uint2 u = ((const uint2*)(hs + (size_t)s * 128))[l32];
        float x = l + erk; x = (x >= 0.f) ? x : NEG_SLOPE * x;
        const float ee = __expf(x);
        es += ee;
        a0 = fmaf(ee, b2f_lo(u.x), a0); a1 = fmaf(ee, b2f_hi(u.x), a1);
        a2 = fmaf(ee, b2f_lo(u.y), a2); a3 = fmaf(ee, b2f_hi(u.y), a3);
    }
    es += __shfl_xor(es, 32);
    a0 += __shfl_xor(a0, 32);
    a1 += __shfl_xor(a1, 32);
    a2 += __shfl_xor(a2, 32);
    a3 += __shfl_xor(a3, 32);
    if (sub == 0) {
        const float inv = (es > 0.f) ? 1.f / es : 0.f;
        float4 o;
        o.x = a0 * inv; o.y = a1 * inv; o.z = a2 * inv; o.w = a3 * inv;
        *(float4*)(out + (size_t)wid * 128 + l32 * 4) = o;
    }
}

extern "C" void kernel_launch(void* const* d_in, const int* in_sizes, int n_in,
                              void* d_out, int out_size, void* d_ws, size_t ws_size,
                              hipStream_t stream) {
    const float* feat_src = (const float*)d_in[0];
    const float* feat_dst = (const float*)d_in[1];
    const float* W_src    = (const float*)d_in[2];
    const float* b_src    = (const float*)d_in[3];
    const float* W_dst    = (const float*)d_in[4];
    const float* b_dst    = (const float*)d_in[5];
    const float* attn     = (const float*)d_in[6];
    const int*   src_idx  = (const int*)d_in[7];
    const int*   dst_idx  = (const int*)d_in[8];
    float* out = (float*)d_out;

    const int n_src  = in_sizes[0] / 128;
    const int n_dst  = in_sizes[1] / 128;
    const int nEdges = in_sizes[7];

    // workspace layout
    __hip_bfloat16* hs = (__hip_bfloat16*)d_ws;            // n_src*128 bf16
    float* el   = (float*)(hs + (size_t)n_src * 128);      // n_src*8
    float* er   = el + (size_t)n_src * 8;                  // n_dst*8
    int*   cnt  = (int*)(er + (size_t)n_dst * 8);          // n_dst
    int*   off  = cnt + n_dst;                             // n_dst+1 (+pad)
    int*   part = off + n_dst + 4;                         // <=1024
    int*   rank = part + 1024;                             // nEdges
    int*   sorted_src = rank + nEdges;                     // nEdges
    // 16B-align the fragment buffers
    uintptr_t p = (uintptr_t)(sorted_src + nEdges);
    p = (p + 15) & ~(uintptr_t)15;
    uint4* wp_src = (uint4*)p;                             // 36*64 uint4
    uint4* wp_dst = wp_src + 36 * 64;                      // 36*64 uint4
    float* c_all  = (float*)(wp_dst + 36 * 64);            // 16 floats

    const int nPart = (n_dst + 1023) / 1024;
    const int eb    = (nEdges + 2047) / 2048;              // 8 edges/thread

    hipMemsetAsync(cnt, 0, (size_t)n_dst * sizeof(int), stream);

    pack_kernel<<<19, 256, 0, stream>>>(W_src, W_dst, b_src, b_dst, attn,
                                        wp_src, wp_dst, c_all);

    mfma_proj_kernel<true ><<<(n_src + 127) / 128, 256, 0, stream>>>(
        feat_src, wp_src, b_src, c_all,     (short*)hs, el, n_src);
    mfma_proj_kernel<false><<<(n_dst + 127) / 128, 256, 0, stream>>>(
        feat_dst, wp_dst, b_dst, c_all + 8, nullptr,    er, n_dst);

    rank_hist_kernel<<<eb, 256, 0, stream>>>(dst_idx, cnt, rank, nEdges);
    scan_part_kernel<<<nPart, 1024, 0, stream>>>(cnt, part, n_dst);
    scan_top_kernel<<<1, 1024, 0, stream>>>(part, off, nPart, n_dst);
    scan_local_kernel<<<nPart, 1024, 0, stream>>>(cnt, part, off, n_dst);
    scatter_kernel<<<eb, 256, 0, stream>>>(src_idx, dst_idx, rank, off, sorted_src, nEdges);

    reduce_kernel<<<(n_dst + 3) / 4, 256, 0, stream>>>(sorted_src, off, hs, el, er, out, n_dst);
}

// Round 6
// 291.574 us; speedup vs baseline: 5.7442x; 1.0496x over previous
//
#include <hip/hip_runtime.h>
#include <hip/hip_bf16.h>

#define NEG_SLOPE 0.2f
#define CNT_STRIDE 16   // one counter per 64B line to kill same-line atomic serialization

typedef __attribute__((ext_vector_type(8))) short bf16x8;
typedef __attribute__((ext_vector_type(4))) float f32x4;

__device__ __forceinline__ float b2f_lo(unsigned u) { return __uint_as_float(u << 16); }
__device__ __forceinline__ float b2f_hi(unsigned u) { return __uint_as_float(u & 0xffff0000u); }

__device__ __forceinline__ short f2b(float x) {
    unsigned u = __float_as_uint(x);
    unsigned r = (u + 0x7fffu + ((u >> 16) & 1u)) >> 16;
    return (short)r;
}

// ---------------------------------------------------------------------------
// 0) Pack W into MFMA B-fragment order (bf16) + fused logit matrix V = W·A'
//    (9th n-tile) and c = b·A'.
// ---------------------------------------------------------------------------
__global__ __launch_bounds__(256) void pack_kernel(
    const float* __restrict__ W_src, const float* __restrict__ W_dst,
    const float* __restrict__ b_src, const float* __restrict__ b_dst,
    const float* __restrict__ attn,  // [8,32]
    uint4* __restrict__ wp_src, uint4* __restrict__ wp_dst,
    float* __restrict__ c_all)       // [16]
{
    const int e = blockIdx.x * 256 + threadIdx.x;
    if (e < 4608) {
        const int which = e / 2304;
        const int e2 = e % 2304;
        const float* W = which ? W_dst : W_src;
        uint4* wp = which ? wp_dst : wp_src;
        const int aoff = which ? 16 : 0;
        short out[8];
        if (e2 < 2048) {                    // W tiles
            const int t = e2 >> 8, q = (e2 >> 6) & 3, l = e2 & 63;
            const int kbase = (l >> 4) * 8 + q * 32;
            const int n = t * 16 + (l & 15);
            #pragma unroll
            for (int j = 0; j < 8; ++j) out[j] = f2b(W[(size_t)(kbase + j) * 128 + n]);
            *(uint4*)&wp[(t * 4 + q) * 64 + l] = *(uint4*)out;
        } else {                            // V tile (fused logits)
            const int e3 = e2 - 2048;
            const int q = e3 >> 6, l = e3 & 63;
            const int kbase = (l >> 4) * 8 + q * 32;
            const int n = l & 15;
            #pragma unroll
            for (int j = 0; j < 8; ++j) {
                float v = 0.f;
                if (n < 8) {
                    for (int dd = 0; dd < 16; ++dd)
                        v += W[(size_t)(kbase + j) * 128 + n * 16 + dd] * attn[n * 32 + aoff + dd];
                }
                out[j] = f2b(v);
            }
            *(uint4*)&wp[(32 + q) * 64 + l] = *(uint4*)out;
        }
    } else if (e < 4624) {                  // c = b·A'
        const int k = e - 4608;
        const int which = k >> 3, kk = k & 7;
        const float* bb = which ? b_dst : b_src;
        const int aoff = which ? 16 : 0;
        float v = 0.f;
        for (int dd = 0; dd < 16; ++dd) v += bb[kk * 16 + dd] * attn[kk * 32 + aoff + dd];
        c_all[k] = v;
    }
}

// ---------------------------------------------------------------------------
// device bodies for the fused kernel
// ---------------------------------------------------------------------------
__device__ __forceinline__ void rank_body(
    const int* __restrict__ dst_idx, int* __restrict__ cnt,
    int* __restrict__ rank, int nEdges, int bx)
{
    const int base = (bx * 256 + threadIdx.x) * 8;
    if (base + 8 <= nEdges) {
        const int4 d0 = *(const int4*)(dst_idx + base);
        const int4 d1 = *(const int4*)(dst_idx + base + 4);
        int4 r0, r1;
        r0.x = atomicAdd(&cnt[d0.x * CNT_STRIDE], 1);
        r0.y = atomicAdd(&cnt[d0.y * CNT_STRIDE], 1);
        r0.z = atomicAdd(&cnt[d0.z * CNT_STRIDE], 1);
        r0.w = atomicAdd(&cnt[d0.w * CNT_STRIDE], 1);
        r1.x = atomicAdd(&cnt[d1.x * CNT_STRIDE], 1);
        r1.y = atomicAdd(&cnt[d1.y * CNT_STRIDE], 1);
        r1.z = atomicAdd(&cnt[d1.z * CNT_STRIDE], 1);
        r1.w = atomicAdd(&cnt[d1.w * CNT_STRIDE], 1);
        *(int4*)(rank + base)     = r0;
        *(int4*)(rank + base + 4) = r1;
    } else {
        for (int e = base; e < nEdges; ++e)
            rank[e] = atomicAdd(&cnt[dst_idx[e] * CNT_STRIDE], 1);
    }
}

template<bool STORE_H>
__device__ __forceinline__ void proj_body(
    const float* __restrict__ feat, const uint4* __restrict__ wp,
    const float* __restrict__ b, const float* __restrict__ cvec,
    short* __restrict__ hs_out, float* __restrict__ el_out,
    int N, int bx)
{
    const int t = threadIdx.x;
    const int lane = t & 63;
    const int w = t >> 6;
    const int m  = lane & 15;
    const int q8 = lane >> 4;
    const int row0 = bx * 128 + w * 32;

    f32x4 acc0[9], acc1[9];
    #pragma unroll
    for (int tt = 0; tt < 8; ++tt) {
        const float bn = b[tt * 16 + m];
        acc0[tt] = (f32x4){bn, bn, bn, bn};
        acc1[tt] = (f32x4){bn, bn, bn, bn};
    }
    acc0[8] = (f32x4){0.f, 0.f, 0.f, 0.f};
    acc1[8] = (f32x4){0.f, 0.f, 0.f, 0.f};

    int rowA0 = row0 + m;      if (rowA0 >= N) rowA0 = N - 1;
    int rowA1 = row0 + 16 + m; if (rowA1 >= N) rowA1 = N - 1;
    const float* f0 = feat + (size_t)rowA0 * 128 + q8 * 8;
    const float* f1 = feat + (size_t)rowA1 * 128 + q8 * 8;
    const bf16x8* wpv = (const bf16x8*)wp;

    #pragma unroll
    for (int kc = 0; kc < 4; ++kc) {
        const float4 fa0 = *(const float4*)(f0 + kc * 32);
        const float4 fb0 = *(const float4*)(f0 + kc * 32 + 4);
        const float4 fa1 = *(const float4*)(f1 + kc * 32);
        const float4 fb1 = *(const float4*)(f1 + kc * 32 + 4);
        bf16x8 a0, a1;
        a0[0]=f2b(fa0.x); a0[1]=f2b(fa0.y); a0[2]=f2b(fa0.z); a0[3]=f2b(fa0.w);
        a0[4]=f2b(fb0.x); a0[5]=f2b(fb0.y); a0[6]=f2b(fb0.z); a0[7]=f2b(fb0.w);
        a1[0]=f2b(fa1.x); a1[1]=f2b(fa1.y); a1[2]=f2b(fa1.z); a1[3]=f2b(fa1.w);
        a1[4]=f2b(fb1.x); a1[5]=f2b(fb1.y); a1[6]=f2b(fb1.z); a1[7]=f2b(fb1.w);
        #pragma unroll
        for (int tt = 0; tt < 8; ++tt) {
            const bf16x8 bf = wpv[(tt * 4 + kc) * 64 + lane];
            acc0[tt] = __builtin_amdgcn_mfma_f32_16x16x32_bf16(a0, bf, acc0[tt], 0, 0, 0);
            acc1[tt] = __builtin_amdgcn_mfma_f32_16x16x32_bf16(a1, bf, acc1[tt], 0, 0, 0);
        }
        {
            const bf16x8 bv = wpv[(32 + kc) * 64 + lane];
            acc0[8] = __builtin_amdgcn_mfma_f32_16x16x32_bf16(a0, bv, acc0[8], 0, 0, 0);
            acc1[8] = __builtin_amdgcn_mfma_f32_16x16x32_bf16(a1, bv, acc1[8], 0, 0, 0);
        }
    }

    #pragma unroll
    for (int half = 0; half < 2; ++half) {
        const f32x4* acc = half ? acc1 : acc0;
        const int rbase = row0 + half * 16 + q8 * 4;
        #pragma unroll
        for (int reg = 0; reg < 4; ++reg) {
            const int row = rbase + reg;
            if (row < N) {
                if (STORE_H) {
                    #pragma unroll
                    for (int tt = 0; tt < 8; ++tt)
                        hs_out[(size_t)row * 128 + tt * 16 + m] = f2b(acc[tt][reg]);
                }
                if (m < 8) el_out[(size_t)row * 8 + m] = acc[8][reg] + cvec[m];
            }
        }
    }
}

// ---------------------------------------------------------------------------
// 1) fused: rank_hist (latency/atomic-bound) + both MFMA projections
//    (MFMA-bound) — disjoint pipes, co-scheduled waves overlap (m114).
//    Rank blocks dispatched first (longest pole).
// ---------------------------------------------------------------------------
__global__ __launch_bounds__(256, 2) void fused_proj_rank_kernel(
    const float* __restrict__ feat_src, const float* __restrict__ feat_dst,
    const uint4* __restrict__ wp_src, const uint4* __restrict__ wp_dst,
    const float* __restrict__ b_src, const float* __restrict__ b_dst,
    const float* __restrict__ c_all,
    short* __restrict__ hs, float* __restrict__ el, float* __restrict__ er,
    const int* __restrict__ dst_idx, int* __restrict__ cnt, int* __restrict__ rank,
    int n_src, int n_dst, int nEdges, int ebBlocks, int pSrcBlocks)
{
    int bx = blockIdx.x;
    if (bx < ebBlocks) { rank_body(dst_idx, cnt, rank, nEdges, bx); return; }
    bx -= ebBlocks;
    if (bx < pSrcBlocks) {
        proj_body<true>(feat_src, wp_src, b_src, c_all, hs, el, n_src, bx);
        return;
    }
    bx -= pSrcBlocks;
    proj_body<false>(feat_dst, wp_dst, b_dst, c_all + 8, nullptr, er, n_dst, bx);
}

// ---------------------------------------------------------------------------
// 2a) partial sums per 1024-block (strided counter read)
// ---------------------------------------------------------------------------
__global__ __launch_bounds__(1024) void scan_part_kernel(
    const int* __restrict__ cnt, int* __restrict__ part, int n)
{
    __shared__ int wsum[16];
    const int t = threadIdx.x;
    const int i = blockIdx.x * 1024 + t;
    int v = (i < n) ? cnt[(size_t)i * CNT_STRIDE] : 0;
    #pragma unroll
    for (int s = 32; s > 0; s >>= 1) v += __shfl_down(v, s, 64);
    if ((t & 63) == 0) wsum[t >> 6] = v;
    __syncthreads();
    if (t < 16) {
        int x = wsum[t];
        #pragma unroll
        for (int s = 8; s > 0; s >>= 1) x += __shfl_down(x, s, 64);
        if (t == 0) part[blockIdx.x] = x;
    }
}

// ---------------------------------------------------------------------------
// 2b) single-block exclusive scan of partials; off[n] = total
// ---------------------------------------------------------------------------
__global__ __launch_bounds__(1024) void scan_top_kernel(
    int* __restrict__ part, int* __restrict__ off, int nPart, int n)
{
    __shared__ int buf[1024];
    const int t = threadIdx.x;
    const int v = (t < nPart) ? part[t] : 0;
    buf[t] = v;
    __syncthreads();
    #pragma unroll
    for (int s = 1; s < 1024; s <<= 1) {
        const int add = (t >= s) ? buf[t - s] : 0;
        __syncthreads();
        buf[t] += add;
        __syncthreads();
    }
    if (t < nPart) part[t] = buf[t] - v;        // exclusive
    if (t == 1023) off[n] = buf[1023];          // total
}

// ---------------------------------------------------------------------------
// 2c) per-block local exclusive scan + base -> off
// ---------------------------------------------------------------------------
__global__ __launch_bounds__(1024) void scan_local_kernel(
    const int* __restrict__ cnt, const int* __restrict__ part,
    int* __restrict__ off, int n)
{
    __shared__ int buf[1024];
    const int t = threadIdx.x;
    const int i = blockIdx.x * 1024 + t;
    const int v = (i < n) ? cnt[(size_t)i * CNT_STRIDE] : 0;
    buf[t] = v;
    __syncthreads();
    #pragma unroll
    for (int s = 1; s < 1024; s <<= 1) {
        const int add = (t >= s) ? buf[t - s] : 0;
        __syncthreads();
        buf[t] += add;
        __syncthreads();
    }
    if (i < n) off[i] = part[blockIdx.x] + buf[t] - v;
}

// ---------------------------------------------------------------------------
// 3) deterministic scatter: pos = off[d] + rank[e]. No atomics.
// ---------------------------------------------------------------------------
__global__ __launch_bounds__(256) void scatter_kernel(
    const int* __restrict__ src_idx, const int* __restrict__ dst_idx,
    const int* __restrict__ rank, const int* __restrict__ off,
    int* __restrict__ sorted_src, int nEdges)
{
    const int base = (blockIdx.x * 256 + threadIdx.x) * 8;
    if (base + 8 <= nEdges) {
        const int4 d0 = *(const int4*)(dst_idx + base);
        const int4 d1 = *(const int4*)(dst_idx + base + 4);
        const int4 r0 = *(const int4*)(rank + base);
        const int4 r1 = *(const int4*)(rank + base + 4);
        const int4 s0 = *(const int4*)(src_idx + base);
        const int4 s1 = *(const int4*)(src_idx + base + 4);
        sorted_src[off[d0.x] + r0.x] = s0.x;
        sorted_src[off[d0.y] + r0.y] = s0.y;
        sorted_src[off[d0.z] + r0.z] = s0.z;
        sorted_src[off[d0.w] + r0.w] = s0.w;
        sorted_src[off[d1.x] + r1.x] = s1.x;
        sorted_src[off[d1.y] + r1.y] = s1.y;
        sorted_src[off[d1.z] + r1.z] = s1.z;
        sorted_src[off[d1.w] + r1.w] = s1.w;
    } else {
        for (int e = base; e < nEdges; ++e)
            sorted_src[off[dst_idx[e]] + rank[e]] = src_idx[e];
    }
}

// ---------------------------------------------------------------------------
// 4) one wave per dst, half-wave per edge, register softmax-aggregation.
// ---------------------------------------------------------------------------
__global__ __launch_bounds__(256) void reduce_kernel(
    const int* __restrict__ sorted_src, const int* __restrict__ off,
    const __hip_bfloat16* __restrict__ hs, // [N_src,128] bf16
    const float* __restrict__ el,     // [N_src,8]
    const float* __restrict__ er,     // [N_dst,8]
    float* __restrict__ out,          // [N_dst,128]
    int n_dst)
{
    const int wid = blockIdx.x * 4 + (threadIdx.x >> 6);
    if (wid >= n_dst) return;
    const int lane = threadIdx.x & 63;
    const int sub  = lane >> 5;
    const int l32  = lane & 31;
    const int k    = l32 >> 2;
    const float erk = er[(size_t)wid * 8 + k];
    const int beg = off[wid], end = off[wid + 1];

    float a0 = 0.f, a1 = 0.f, a2 = 0.f, a3 = 0.f, es = 0.f;
    int i = beg + sub;
    for (; i + 2 < end; i += 4) {
        const int sA = sorted_src[i];
        const int sB = sorted_src[i + 2];
        const float lA = el[(size_t)sA * 8 + k];
        const float lB = el[(size_t)sB * 8 + k];
        const uint2 uA = ((const uint2*)(hs + (size_t)sA * 128))[l32];
        const uint2 uB = ((const uint2*)(hs + (size_t)sB * 128))[l32];
        float xA = lA + erk; xA = (xA >= 0.f) ? xA : NEG_SLOPE * xA;
        float xB = lB + erk; xB = (xB >= 0.f) ? xB : NEG_SLOPE * xB;
        const float eA = __expf(xA);
        const float eB = __expf(xB);
        es += eA + eB;
        a0 = fmaf(eA, b2f_lo(uA.x), a0); a1 = fmaf(eA, b2f_hi(uA.x), a1);
        a2 = fmaf(eA, b2f_lo(uA.y), a2); a3 = fmaf(eA, b2f_hi(uA.y), a3);
        a0 = fmaf(eB, b2f_lo(uB.x), a0); a1 = fmaf(eB, b2f_hi(uB.x), a1);
        a2 = fmaf(eB, b2f_lo(uB.y), a2); a3 = fmaf(eB, b2f_hi(uB.y), a3);
    }
    for (; i < end; i += 2) {
        const int s = sorted_src[i];
        const float l = el[(size_t)s * 8 + k];
        const uint2 u = ((const uint2*)(hs + (size_t)s * 128))[l32];
        float x = l + erk; x = (x >= 0.f) ? x : NEG_SLOPE * x;
        const float ee = __expf(x);
        es += ee;
        a0 = fmaf(ee, b2f_lo(u.x), a0); a1 = fmaf(ee, b2f_hi(u.x), a1);
        a2 = fmaf(ee, b2f_lo(u.y), a2); a3 = fmaf(ee, b2f_hi(u.y), a3);
    }
    es += __shfl_xor(es, 32);
    a0 += __shfl_xor(a0, 32);
    a1 += __shfl_xor(a1, 32);
    a2 += __shfl_xor(a2, 32);
    a3 += __shfl_xor(a3, 32);
    if (sub == 0) {
        const float inv = (es > 0.f) ? 1.f / es : 0.f;
        float4 o;
        o.x = a0 * inv; o.y = a1 * inv; o.z = a2 * inv; o.w = a3 * inv;
        *(float4*)(out + (size_t)wid * 128 + l32 * 4) = o;
    }
}

extern "C" void kernel_launch(void* const* d_in, const int* in_sizes, int n_in,
                              void* d_out, int out_size, void* d_ws, size_t ws_size,
                              hipStream_t stream) {
    const float* feat_src = (const float*)d_in[0];
    const float* feat_dst = (const float*)d_in[1];
    const float* W_src    = (const float*)d_in[2];
    const float* b_src    = (const float*)d_in[3];
    const float* W_dst    = (const float*)d_in[4];
    const float* b_dst    = (const float*)d_in[5];
    const float* attn     = (const float*)d_in[6];
    const int*   src_idx  = (const int*)d_in[7];
    const int*   dst_idx  = (const int*)d_in[8];
    float* out = (float*)d_out;

    const int n_src  = in_sizes[0] / 128;
    const int n_dst  = in_sizes[1] / 128;
    const int nEdges = in_sizes[7];

    // workspace layout
    __hip_bfloat16* hs = (__hip_bfloat16*)d_ws;            // n_src*128 bf16
    float* el   = (float*)(hs + (size_t)n_src * 128);      // n_src*8
    float* er   = el + (size_t)n_src * 8;                  // n_dst*8
    int*   off  = (int*)(er + (size_t)n_dst * 8);          // n_dst+1 (+pad)
    int*   part = off + n_dst + 4;                         // <=1024
    int*   rank = part + 1024;                             // nEdges
    int*   sorted_src = rank + nEdges;                     // nEdges
    int*   cnt  = sorted_src + nEdges;                     // n_dst*CNT_STRIDE (padded)
    uintptr_t p = (uintptr_t)(cnt + (size_t)n_dst * CNT_STRIDE);
    p = (p + 15) & ~(uintptr_t)15;
    uint4* wp_src = (uint4*)p;                             // 36*64 uint4
    uint4* wp_dst = wp_src + 36 * 64;                      // 36*64 uint4
    float* c_all  = (float*)(wp_dst + 36 * 64);            // 16 floats

    const int nPart = (n_dst + 1023) / 1024;
    const int eb    = (nEdges + 2047) / 2048;              // 8 edges/thread
    const int pSrc  = (n_src + 127) / 128;
    const int pDst  = (n_dst + 127) / 128;

    hipMemsetAsync(cnt, 0, (size_t)n_dst * CNT_STRIDE * sizeof(int), stream);

    pack_kernel<<<19, 256, 0, stream>>>(W_src, W_dst, b_src, b_dst, attn,
                                        wp_src, wp_dst, c_all);

    fused_proj_rank_kernel<<<eb + pSrc + pDst, 256, 0, stream>>>(
        feat_src, feat_dst, wp_src, wp_dst, b_src, b_dst, c_all,
        (short*)hs, el, er, dst_idx, cnt, rank,
        n_src, n_dst, nEdges, eb, pSrc);

    scan_part_kernel<<<nPart, 1024, 0, stream>>>(cnt, part, n_dst);
    scan_top_kernel<<<1, 1024, 0, stream>>>(part, off, nPart, n_dst);
    scan_local_kernel<<<nPart, 1024, 0, stream>>>(cnt, part, off, n_dst);
    scatter_kernel<<<eb, 256, 0, stream>>>(src_idx, dst_idx, rank, off, sorted_src, nEdges);

    reduce_kernel<<<(n_dst + 3) / 4, 256, 0, stream>>>(sorted_src, off, hs, el, er, out, n_dst);
}

// Round 7
// 248.533 us; speedup vs baseline: 6.7389x; 1.1732x over previous
//
#include <hip/hip_runtime.h>
#include <hip/hip_bf16.h>

#define NEG_SLOPE 0.2f
#define EPB  8192   // edges per coarse-sort block
#define MAXC 2048   // max coarse bins (= ceil(n_dst/32)); 50000/32 = 1563

typedef __attribute__((ext_vector_type(8))) short bf16x8;
typedef __attribute__((ext_vector_type(4))) float f32x4;

__device__ __forceinline__ float b2f_lo(unsigned u) { return __uint_as_float(u << 16); }
__device__ __forceinline__ float b2f_hi(unsigned u) { return __uint_as_float(u & 0xffff0000u); }

__device__ __forceinline__ short f2b(float x) {
    unsigned u = __float_as_uint(x);
    unsigned r = (u + 0x7fffu + ((u >> 16) & 1u)) >> 16;
    return (short)r;
}

// ---------------------------------------------------------------------------
// 0) Pack W into MFMA B-fragment order (bf16) + fused logit matrix V = W·A'
//    (9th n-tile) and c = b·A'.
// ---------------------------------------------------------------------------
__global__ __launch_bounds__(256) void pack_kernel(
    const float* __restrict__ W_src, const float* __restrict__ W_dst,
    const float* __restrict__ b_src, const float* __restrict__ b_dst,
    const float* __restrict__ attn,  // [8,32]
    uint4* __restrict__ wp_src, uint4* __restrict__ wp_dst,
    float* __restrict__ c_all)       // [16]
{
    const int e = blockIdx.x * 256 + threadIdx.x;
    if (e < 4608) {
        const int which = e / 2304;
        const int e2 = e % 2304;
        const float* W = which ? W_dst : W_src;
        uint4* wp = which ? wp_dst : wp_src;
        const int aoff = which ? 16 : 0;
        short out[8];
        if (e2 < 2048) {                    // W tiles
            const int t = e2 >> 8, q = (e2 >> 6) & 3, l = e2 & 63;
            const int kbase = (l >> 4) * 8 + q * 32;
            const int n = t * 16 + (l & 15);
            #pragma unroll
            for (int j = 0; j < 8; ++j) out[j] = f2b(W[(size_t)(kbase + j) * 128 + n]);
            *(uint4*)&wp[(t * 4 + q) * 64 + l] = *(uint4*)out;
        } else {                            // V tile (fused logits)
            const int e3 = e2 - 2048;
            const int q = e3 >> 6, l = e3 & 63;
            const int kbase = (l >> 4) * 8 + q * 32;
            const int n = l & 15;
            #pragma unroll
            for (int j = 0; j < 8; ++j) {
                float v = 0.f;
                if (n < 8) {
                    for (int dd = 0; dd < 16; ++dd)
                        v += W[(size_t)(kbase + j) * 128 + n * 16 + dd] * attn[n * 32 + aoff + dd];
                }
                out[j] = f2b(v);
            }
            *(uint4*)&wp[(32 + q) * 64 + l] = *(uint4*)out;
        }
    } else if (e < 4624) {                  // c = b·A'
        const int k = e - 4608;
        const int which = k >> 3, kk = k & 7;
        const float* bb = which ? b_dst : b_src;
        const int aoff = which ? 16 : 0;
        float v = 0.f;
        for (int dd = 0; dd < 16; ++dd) v += bb[kk * 16 + dd] * attn[kk * 32 + aoff + dd];
        c_all[k] = v;
    }
}

// ---------------------------------------------------------------------------
// coarse histogram body (LDS, no global atomics): H[bin][block] matrix
// ---------------------------------------------------------------------------
__device__ __forceinline__ void hist_body(
    const int* __restrict__ dst_idx, int* __restrict__ Hmat,
    int nEdges, int nCoarse, int nCB, int bx)
{
    __shared__ int h[MAXC];
    const int t = threadIdx.x;
    for (int i = t; i < nCoarse; i += 256) h[i] = 0;
    __syncthreads();
    const int e0 = bx * EPB;
    const int e1 = min(e0 + EPB, nEdges);
    for (int e = e0 + t; e < e1; e += 256) atomicAdd(&h[dst_idx[e] >> 5], 1);
    __syncthreads();
    for (int i = t; i < nCoarse; i += 256) Hmat[(size_t)i * nCB + bx] = h[i];
}

// ---------------------------------------------------------------------------
// MFMA projection body: h = feat·W + b (bf16 in, fp32 acc), fused logit via
// 9th n-tile. Wave = 2 m-tiles (32 rows); block = 128 rows.
// ---------------------------------------------------------------------------
template<bool STORE_H>
__device__ __forceinline__ void proj_body(
    const float* __restrict__ feat, const uint4* __restrict__ wp,
    const float* __restrict__ b, const float* __restrict__ cvec,
    short* __restrict__ hs_out, float* __restrict__ el_out,
    int N, int bx)
{
    const int t = threadIdx.x;
    const int lane = t & 63;
    const int w = t >> 6;
    const int m  = lane & 15;
    const int q8 = lane >> 4;
    const int row0 = bx * 128 + w * 32;

    f32x4 acc0[9], acc1[9];
    #pragma unroll
    for (int tt = 0; tt < 8; ++tt) {
        const float bn = b[tt * 16 + m];
        acc0[tt] = (f32x4){bn, bn, bn, bn};
        acc1[tt] = (f32x4){bn, bn, bn, bn};
    }
    acc0[8] = (f32x4){0.f, 0.f, 0.f, 0.f};
    acc1[8] = (f32x4){0.f, 0.f, 0.f, 0.f};

    int rowA0 = row0 + m;      if (rowA0 >= N) rowA0 = N - 1;
    int rowA1 = row0 + 16 + m; if (rowA1 >= N) rowA1 = N - 1;
    const float* f0 = feat + (size_t)rowA0 * 128 + q8 * 8;
    const float* f1 = feat + (size_t)rowA1 * 128 + q8 * 8;
    const bf16x8* wpv = (const bf16x8*)wp;

    #pragma unroll
    for (int kc = 0; kc < 4; ++kc) {
        const float4 fa0 = *(const float4*)(f0 + kc * 32);
        const float4 fb0 = *(const float4*)(f0 + kc * 32 + 4);
        const float4 fa1 = *(const float4*)(f1 + kc * 32);
        const float4 fb1 = *(const float4*)(f1 + kc * 32 + 4);
        bf16x8 a0, a1;
        a0[0]=f2b(fa0.x); a0[1]=f2b(fa0.y); a0[2]=f2b(fa0.z); a0[3]=f2b(fa0.w);
        a0[4]=f2b(fb0.x); a0[5]=f2b(fb0.y); a0[6]=f2b(fb0.z); a0[7]=f2b(fb0.w);
        a1[0]=f2b(fa1.x); a1[1]=f2b(fa1.y); a1[2]=f2b(fa1.z); a1[3]=f2b(fa1.w);
        a1[4]=f2b(fb1.x); a1[5]=f2b(fb1.y); a1[6]=f2b(fb1.z); a1[7]=f2b(fb1.w);
        #pragma unroll
        for (int tt = 0; tt < 8; ++tt) {
            const bf16x8 bf = wpv[(tt * 4 + kc) * 64 + lane];
            acc0[tt] = __builtin_amdgcn_mfma_f32_16x16x32_bf16(a0, bf, acc0[tt], 0, 0, 0);
            acc1[tt] = __builtin_amdgcn_mfma_f32_16x16x32_bf16(a1, bf, acc1[tt], 0, 0, 0);
        }
        {
            const bf16x8 bv = wpv[(32 + kc) * 64 + lane];
            acc0[8] = __builtin_amdgcn_mfma_f32_16x16x32_bf16(a0, bv, acc0[8], 0, 0, 0);
            acc1[8] = __builtin_amdgcn_mfma_f32_16x16x32_bf16(a1, bv, acc1[8], 0, 0, 0);
        }
    }

    #pragma unroll
    for (int half = 0; half < 2; ++half) {
        const f32x4* acc = half ? acc1 : acc0;
        const int rbase = row0 + half * 16 + q8 * 4;
        #pragma unroll
        for (int reg = 0; reg < 4; ++reg) {
            const int row = rbase + reg;
            if (row < N) {
                if (STORE_H) {
                    #pragma unroll
                    for (int tt = 0; tt < 8; ++tt)
                        hs_out[(size_t)row * 128 + tt * 16 + m] = f2b(acc[tt][reg]);
                }
                if (m < 8) el_out[(size_t)row * 8 + m] = acc[8][reg] + cvec[m];
            }
        }
    }
}

// ---------------------------------------------------------------------------
// 1) fused: coarse histogram (LDS/memory) + both MFMA projections — disjoint
//    pipes, co-scheduled waves overlap.
// ---------------------------------------------------------------------------
__global__ __launch_bounds__(256, 2) void fused_proj_hist_kernel(
    const float* __restrict__ feat_src, const float* __restrict__ feat_dst,
    const uint4* __restrict__ wp_src, const uint4* __restrict__ wp_dst,
    const float* __restrict__ b_src, const float* __restrict__ b_dst,
    const float* __restrict__ c_all,
    short* __restrict__ hs, float* __restrict__ el, float* __restrict__ er,
    const int* __restrict__ dst_idx, int* __restrict__ Hmat,
    int n_src, int n_dst, int nEdges, int nCoarse, int nCB, int pSrcBlocks)
{
    int bx = blockIdx.x;
    if (bx < nCB) { hist_body(dst_idx, Hmat, nEdges, nCoarse, nCB, bx); return; }
    bx -= nCB;
    if (bx < pSrcBlocks) {
        proj_body<true>(feat_src, wp_src, b_src, c_all, hs, el, n_src, bx);
        return;
    }
    bx -= pSrcBlocks;
    proj_body<false>(feat_dst, wp_dst, b_dst, c_all + 8, nullptr, er, n_dst, bx);
}

// ---------------------------------------------------------------------------
// 2a) partial sums per 1024-block over flat array
// ---------------------------------------------------------------------------
__global__ __launch_bounds__(1024) void scan_part_kernel(
    const int* __restrict__ cnt, int* __restrict__ part, int n)
{
    __shared__ int wsum[16];
    const int t = threadIdx.x;
    const int i = blockIdx.x * 1024 + t;
    int v = (i < n) ? cnt[i] : 0;
    #pragma unroll
    for (int s = 32; s > 0; s >>= 1) v += __shfl_down(v, s, 64);
    if ((t & 63) == 0) wsum[t >> 6] = v;
    __syncthreads();
    if (t < 16) {
        int x = wsum[t];
        #pragma unroll
        for (int s = 8; s > 0; s >>= 1) x += __shfl_down(x, s, 64);
        if (t == 0) part[blockIdx.x] = x;
    }
}

// ---------------------------------------------------------------------------
// 2b) single-block exclusive scan of partials; S[n] = total
// ---------------------------------------------------------------------------
__global__ __launch_bounds__(1024) void scan_top_kernel(
    int* __restrict__ part, int* __restrict__ S, int nPart, int n)
{
    __shared__ int buf[1024];
    const int t = threadIdx.x;
    const int v = (t < nPart) ? part[t] : 0;
    buf[t] = v;
    __syncthreads();
    #pragma unroll
    for (int s = 1; s < 1024; s <<= 1) {
        const int add = (t >= s) ? buf[t - s] : 0;
        __syncthreads();
        buf[t] += add;
        __syncthreads();
    }
    if (t < nPart) part[t] = buf[t] - v;        // exclusive
    if (t == 1023) S[n] = buf[1023];            // total
}

// ---------------------------------------------------------------------------
// 2c) per-block local exclusive scan + base -> S
// ---------------------------------------------------------------------------
__global__ __launch_bounds__(1024) void scan_local_kernel(
    const int* __restrict__ cnt, const int* __restrict__ part,
    int* __restrict__ S, int n)
{
    __shared__ int buf[1024];
    const int t = threadIdx.x;
    const int i = blockIdx.x * 1024 + t;
    const int v = (i < n) ? cnt[i] : 0;
    buf[t] = v;
    __syncthreads();
    #pragma unroll
    for (int s = 1; s < 1024; s <<= 1) {
        const int add = (t >= s) ? buf[t - s] : 0;
        __syncthreads();
        buf[t] += add;
        __syncthreads();
    }
    if (i < n) S[i] = part[blockIdx.x] + buf[t] - v;
}

// ---------------------------------------------------------------------------
// 3) coarse scatter: re-read edges, local rank via LDS atomic, write packed
//    (src<<5 | dst&31) at pre-scanned position. ZERO global atomics.
// ---------------------------------------------------------------------------
__global__ __launch_bounds__(256) void coarse_scatter_kernel(
    const int* __restrict__ src_idx, const int* __restrict__ dst_idx,
    const int* __restrict__ S, int* __restrict__ coarse,
    int nEdges, int nCoarse, int nCB)
{
    __shared__ int base_s[MAXC];
    __shared__ int cur_s[MAXC];
    const int t = threadIdx.x, bx = blockIdx.x;
    for (int i = t; i < nCoarse; i += 256) {
        base_s[i] = S[(size_t)i * nCB + bx];
        cur_s[i]  = 0;
    }
    __syncthreads();
    const int e0 = bx * EPB;
    const int e1 = min(e0 + EPB, nEdges);
    for (int e = e0 + t; e < e1; e += 256) {
        const int d = dst_idx[e];
        const int s = src_idx[e];
        const int bin = d >> 5;
        const int lr = atomicAdd(&cur_s[bin], 1);
        coarse[base_s[bin] + lr] = (s << 5) | (d & 31);
    }
}

// ---------------------------------------------------------------------------
// 4) fine sort: one block per coarse bin (32 dsts). LDS 32-bin counting
//    sort; writes sorted_src and per-dst off[].
// ---------------------------------------------------------------------------
__global__ __launch_bounds__(256) void fine_sort_kernel(
    const int* __restrict__ coarse, const int* __restrict__ S,
    int* __restrict__ off, int* __restrict__ sorted_src,
    int nEdges, int n_dst, int nCoarse, int nCB)
{
    __shared__ int h[32];
    __shared__ int cu[32];
    const int t = threadIdx.x, c = blockIdx.x;
    const int base = S[(size_t)c * nCB];
    const int endp = (c + 1 < nCoarse) ? S[(size_t)(c + 1) * nCB] : nEdges;
    if (t < 32) h[t] = 0;
    __syncthreads();
    for (int i = base + t; i < endp; i += 256) atomicAdd(&h[coarse[i] & 31], 1);
    __syncthreads();
    if (t == 0) {
        int run = 0;
        #pragma unroll
        for (int j = 0; j < 32; ++j) {
            cu[j] = run;
            const int d = c * 32 + j;
            if (d < n_dst) off[d] = base + run;
            run += h[j];
        }
    }
    __syncthreads();
    for (int i = base + t; i < endp; i += 256) {
        const int v = coarse[i];
        const int p = atomicAdd(&cu[v & 31], 1);
        sorted_src[base + p] = v >> 5;
    }
    if (c == 0 && t == 0) off[n_dst] = nEdges;
}

// ---------------------------------------------------------------------------
// 5) one wave per dst, half-wave per edge, register softmax-aggregation.
// ---------------------------------------------------------------------------
__global__ __launch_bounds__(256) void reduce_kernel(
    const int* __restrict__ sorted_src, const int* __restrict__ off,
    const __hip_bfloat16* __restrict__ hs, // [N_src,128] bf16
    const float* __restrict__ el,     // [N_src,8]
    const float* __restrict__ er,     // [N_dst,8]
    float* __restrict__ out,          // [N_dst,128]
    int n_dst)
{
    const int wid = blockIdx.x * 4 + (threadIdx.x >> 6);
    if (wid >= n_dst) return;
    const int lane = threadIdx.x & 63;
    const int sub  = lane >> 5;
    const int l32  = lane & 31;
    const int k    = l32 >> 2;
    const float erk = er[(size_t)wid * 8 + k];
    const int beg = off[wid], end = off[wid + 1];

    float a0 = 0.f, a1 = 0.f, a2 = 0.f, a3 = 0.f, es = 0.f;
    int i = beg + sub;
    for (; i + 2 < end; i += 4) {
        const int sA = sorted_src[i];
        const int sB = sorted_src[i + 2];
        const float lA = el[(size_t)sA * 8 + k];
        const float lB = el[(size_t)sB * 8 + k];
        const uint2 uA = ((const uint2*)(hs + (size_t)sA * 128))[l32];
        const uint2 uB = ((const uint2*)(hs + (size_t)sB * 128))[l32];
        float xA = lA + erk; xA = (xA >= 0.f) ? xA : NEG_SLOPE * xA;
        float xB = lB + erk; xB = (xB >= 0.f) ? xB : NEG_SLOPE * xB;
        const float eA = __expf(xA);
        const float eB = __expf(xB);
        es += eA + eB;
        a0 = fmaf(eA, b2f_lo(uA.x), a0); a1 = fmaf(eA, b2f_hi(uA.x), a1);
        a2 = fmaf(eA, b2f_lo(uA.y), a2); a3 = fmaf(eA, b2f_hi(uA.y), a3);
        a0 = fmaf(eB, b2f_lo(uB.x), a0); a1 = fmaf(eB, b2f_hi(uB.x), a1);
        a2 = fmaf(eB, b2f_lo(uB.y), a2); a3 = fmaf(eB, b2f_hi(uB.y), a3);
    }
    for (; i < end; i += 2) {
        const int s = sorted_src[i];
        const float l = el[(size_t)s * 8 + k];
        const uint2 u = ((const uint2*)(hs + (size_t)s * 128))[l32];
        float x = l + erk; x = (x >= 0.f) ? x : NEG_SLOPE * x;
        const float ee = __expf(x);
        es += ee;
        a0 = fmaf(ee, b2f_lo(u.x), a0); a1 = fmaf(ee, b2f_hi(u.x), a1);
        a2 = fmaf(ee, b2f_lo(u.y), a2); a3 = fmaf(ee, b2f_hi(u.y), a3);
    }
    es += __shfl_xor(es, 32);
    a0 += __shfl_xor(a0, 32);
    a1 += __shfl_xor(a1, 32);
    a2 += __shfl_xor(a2, 32);
    a3 += __shfl_xor(a3, 32);
    if (sub == 0) {
        const float inv = (es > 0.f) ? 1.f / es : 0.f;
        float4 o;
        o.x = a0 * inv; o.y = a1 * inv; o.z = a2 * inv; o.w = a3 * inv;
        *(float4*)(out + (size_t)wid * 128 + l32 * 4) = o;
    }
}

extern "C" void kernel_launch(void* const* d_in, const int* in_sizes, int n_in,
                              void* d_out, int out_size, void* d_ws, size_t ws_size,
                              hipStream_t stream) {
    const float* feat_src = (const float*)d_in[0];
    const float* feat_dst = (const float*)d_in[1];
    const float* W_src    = (const float*)d_in[2];
    const float* b_src    = (const float*)d_in[3];
    const float* W_dst    = (const float*)d_in[4];
    const float* b_dst    = (const float*)d_in[5];
    const float* attn     = (const float*)d_in[6];
    const int*   src_idx  = (const int*)d_in[7];
    const int*   dst_idx  = (const int*)d_in[8];
    float* out = (float*)d_out;

    const int n_src  = in_sizes[0] / 128;
    const int n_dst  = in_sizes[1] / 128;
    const int nEdges = in_sizes[7];

    const int nCoarse = (n_dst + 31) >> 5;                 // 1563
    const int nCB     = (nEdges + EPB - 1) / EPB;          // 196
    const int nH      = nCoarse * nCB;                     // ~306k
    const int nPart   = (nH + 1023) / 1024;                // ~300
    const int pSrc    = (n_src + 127) / 128;
    const int pDst    = (n_dst + 127) / 128;

    // workspace layout
    __hip_bfloat16* hs = (__hip_bfloat16*)d_ws;            // n_src*128 bf16
    float* el   = (float*)(hs + (size_t)n_src * 128);      // n_src*8
    float* er   = el + (size_t)n_src * 8;                  // n_dst*8
    int*   off  = (int*)(er + (size_t)n_dst * 8);          // n_dst+1 (+pad)
    int*   part = off + n_dst + 4;                         // <=1024
    int*   Hmat = part + 1024;                             // nH
    int*   Sarr = Hmat + nH;                               // nH+1 (+pad)
    int*   coarse = Sarr + nH + 4;                         // nEdges (packed)
    int*   sorted_src = coarse + nEdges;                   // nEdges
    uintptr_t p = (uintptr_t)(sorted_src + nEdges);
    p = (p + 15) & ~(uintptr_t)15;
    uint4* wp_src = (uint4*)p;                             // 36*64 uint4
    uint4* wp_dst = wp_src + 36 * 64;                      // 36*64 uint4
    float* c_all  = (float*)(wp_dst + 36 * 64);            // 16 floats

    pack_kernel<<<19, 256, 0, stream>>>(W_src, W_dst, b_src, b_dst, attn,
                                        wp_src, wp_dst, c_all);

    fused_proj_hist_kernel<<<nCB + pSrc + pDst, 256, 0, stream>>>(
        feat_src, feat_dst, wp_src, wp_dst, b_src, b_dst, c_all,
        (short*)hs, el, er, dst_idx, Hmat,
        n_src, n_dst, nEdges, nCoarse, nCB, pSrc);

    scan_part_kernel<<<nPart, 1024, 0, stream>>>(Hmat, part, nH);
    scan_top_kernel<<<1, 1024, 0, stream>>>(part, Sarr, nPart, nH);
    scan_local_kernel<<<nPart, 1024, 0, stream>>>(Hmat, part, Sarr, nH);

    coarse_scatter_kernel<<<nCB, 256, 0, stream>>>(src_idx, dst_idx, Sarr,
                                                   coarse, nEdges, nCoarse, nCB);
    fine_sort_kernel<<<nCoarse, 256, 0, stream>>>(coarse, Sarr, off, sorted_src,
                                                  nEdges, n_dst, nCoarse, nCB);

    reduce_kernel<<<(n_dst + 3) / 4, 256, 0, stream>>>(sorted_src, off, hs, el, er, out, n_dst);
}